// Round 2
// baseline (478.913 us; speedup 1.0000x reference)
//
#include <hip/hip_runtime.h>
#include <hip/hip_bf16.h>
#include <stdint.h>

// Problem: B=8, N=8192, C=256, H=8, D=32, P=64, F=4C=1024
// Canonical internal layout qkvv: [part(4)][b(8)][h*32+d(256)][n(8192)] bf16, n contiguous.
// Dtype-adaptive: k_detect sniffs whether inputs are fp32 or bf16; k_convert_*
// canonicalizes everything to bf16 workspace buffers; k_out writes fp32 or bf16.

typedef __attribute__((ext_vector_type(8))) __bf16 bf16x8;
typedef __attribute__((ext_vector_type(4))) float f32x4;

#define MFMA(a, b, c) __builtin_amdgcn_mfma_f32_16x16x32_bf16((a), (b), (c), 0, 0, 0)

__device__ __forceinline__ void gl2lds16(const __bf16* g, __bf16* l) {
  __builtin_amdgcn_global_load_lds(
      (const __attribute__((address_space(1))) void*)(const void*)g,
      (__attribute__((address_space(3))) void*)(void*)l, 16, 0, 0);
}

// ---------------- K0a: dtype detection --------------------------------------
// If x is fp32 read as u16, even halves are mantissa bytes -> exponent field
// uniform -> ~25% of samples have exp>=0xC0. Genuine bf16 N(0,1): zero.
__global__ __launch_bounds__(256) void k_detect(const unsigned short* __restrict__ xr,
                                                int* __restrict__ flag) {
  __shared__ int cnt;
  if (threadIdx.x == 0) cnt = 0;
  __syncthreads();
  int c = 0;
  for (int i = threadIdx.x; i < 8192; i += 256) {
    const int e = (xr[i] >> 7) & 0xFF;
    c += (e >= 0xC0) ? 1 : 0;
  }
  atomicAdd(&cnt, c);
  __syncthreads();
  if (threadIdx.x == 0) *flag = (cnt > 100) ? 1 : 0;
}

// ---------------- K0b: canonicalize x to bf16 --------------------------------
__global__ __launch_bounds__(256) void k_convert_x(const void* __restrict__ src,
                                                   __bf16* __restrict__ dst,
                                                   const int* __restrict__ flag) {
  const int i = (blockIdx.x * 256 + threadIdx.x) * 8;  // < 16777216
  if (*flag) {
    const float* s = (const float*)src;
    bf16x8 v;
#pragma unroll
    for (int j = 0; j < 8; ++j) v[j] = (__bf16)s[i + j];
    *(bf16x8*)(dst + i) = v;
  } else {
    *(bf16x8*)(dst + i) = *(const bf16x8*)((const __bf16*)src + i);
  }
}

// ---------------- K0c: canonicalize the 11 weight/bias/temp inputs -----------
// cw element offsets:
//  Wq 0 | WE 262144 | bE 786432 | WF 786496 | bF 1310784 | Wo1 1310848
//  bo1 1343616 | Wo2 1343744 | bo2 1376512 | temp1 1376640 | temp2 1376648 | end 1376656
__global__ __launch_bounds__(256) void k_convert_w(
    const void* s0, const void* s1, const void* s2, const void* s3, const void* s4,
    const void* s5, const void* s6, const void* s7, const void* s8, const void* s9,
    const void* s10, __bf16* __restrict__ cw, const int* __restrict__ flag) {
  const int i = (blockIdx.x * 256 + threadIdx.x) * 8;
  if (i >= 1376656) return;
  const void* s;
  int base;
  if (i < 262144)        { s = s0;  base = 0; }
  else if (i < 786432)   { s = s1;  base = 262144; }
  else if (i < 786496)   { s = s2;  base = 786432; }
  else if (i < 1310784)  { s = s3;  base = 786496; }
  else if (i < 1310848)  { s = s4;  base = 1310784; }
  else if (i < 1343616)  { s = s5;  base = 1310848; }
  else if (i < 1343744)  { s = s6;  base = 1343616; }
  else if (i < 1376512)  { s = s7;  base = 1343744; }
  else if (i < 1376640)  { s = s8;  base = 1376512; }
  else if (i < 1376648)  { s = s9;  base = 1376640; }
  else                   { s = s10; base = 1376648; }
  const int li = i - base;
  if (*flag) {
    const float* sf = (const float*)s;
#pragma unroll
    for (int j = 0; j < 8; ++j) cw[i + j] = (__bf16)sf[li + j];
  } else {
    const __bf16* sb = (const __bf16*)s;
#pragma unroll
    for (int j = 0; j < 8; ++j) cw[i + j] = sb[li + j];
  }
}

// ---------------- K1: qkvv = x @ Wqkvv^T, stored transposed ----------------
// C[f, tok] = sum_c Wq[f,c] * x[tok,c].  M=1024 (f), N=65536 (tok), K=256.
__global__ __launch_bounds__(256) void k_qkvv(const __bf16* __restrict__ x,
                                              const __bf16* __restrict__ Wq,
                                              __bf16* __restrict__ qkvv) {
  __shared__ alignas(16) __bf16 As[128 * 32];
  __shared__ alignas(16) __bf16 Bs[128 * 32];
  const int t = threadIdx.x, lane = t & 63;
  const int wr = t >> 7, wc = (t >> 6) & 1;
  const int f0 = blockIdx.y * 128;
  const int t0 = blockIdx.x * 128;
  f32x4 acc[4][4] = {};
  const int r = t >> 2, c8 = (t & 3) * 8;
  for (int k0 = 0; k0 < 256; k0 += 32) {
#pragma unroll
    for (int i = 0; i < 2; ++i) {
      gl2lds16(Wq + (size_t)(f0 + i * 64 + r) * 256 + k0 + c8, As + i * 2048 + t * 8);
      gl2lds16(x + (size_t)(t0 + i * 64 + r) * 256 + k0 + c8, Bs + i * 2048 + t * 8);
    }
    __syncthreads();
    bf16x8 af[4], bfr[4];
#pragma unroll
    for (int i = 0; i < 4; ++i) {
      af[i] = *(const bf16x8*)(As + (wr * 64 + i * 16 + (lane & 15)) * 32 + (lane >> 4) * 8);
      bfr[i] = *(const bf16x8*)(Bs + (wc * 64 + i * 16 + (lane & 15)) * 32 + (lane >> 4) * 8);
    }
#pragma unroll
    for (int i = 0; i < 4; ++i)
#pragma unroll
      for (int j = 0; j < 4; ++j) acc[i][j] = MFMA(af[i], bfr[j], acc[i][j]);
    __syncthreads();
  }
  const int b = t0 >> 13;
#pragma unroll
  for (int i = 0; i < 4; ++i) {
#pragma unroll
    for (int j = 0; j < 4; ++j) {
      const int tok = t0 + wc * 64 + j * 16 + (lane & 15);
      const int n = tok & 8191;
#pragma unroll
      for (int rr = 0; rr < 4; ++rr) {
        const int f = f0 + wr * 64 + i * 16 + (lane >> 4) * 4 + rr;
        qkvv[(size_t)(((f >> 8) * 8 + b) * 256 + (f & 255)) * 8192 + n] = (__bf16)acc[i][j][rr];
      }
    }
  }
}

// ---------------- K2: inverse L2 norms over n for q (part0) and k (part1) ----
__global__ __launch_bounds__(256) void k_norms(const __bf16* __restrict__ qkvv,
                                               float* __restrict__ qinv,
                                               float* __restrict__ kinv) {
  const int row = blockIdx.x, which = blockIdx.y;  // row in [0,2048)
  const __bf16* p = qkvv + (size_t)(which * 2048 + row) * 8192;
  float s = 0.f;
  for (int i = threadIdx.x; i < 8192; i += 256) {
    const float v = (float)p[i];
    s += v * v;
  }
#pragma unroll
  for (int off = 32; off; off >>= 1) s += __shfl_down(s, off, 64);
  __shared__ float red[4];
  if ((threadIdx.x & 63) == 0) red[threadIdx.x >> 6] = s;
  __syncthreads();
  if (threadIdx.x == 0) {
    const float tot = red[0] + red[1] + red[2] + red[3];
    const float inv = 1.0f / fmaxf(sqrtf(tot), 1e-12f);
    (which ? kinv : qinv)[row] = inv;
  }
}

// ---------------- K3: k_proj / v_proj partial GEMMs (K-split) ----------------
// C[r, p] = sum_n A[r,n] * W[p,n];  r in [0,2048), p in [0,64), K-chunk = 512.
__global__ __launch_bounds__(256) void k_proj_part(const __bf16* __restrict__ qkvv,
                                                   const __bf16* __restrict__ WE,
                                                   const __bf16* __restrict__ WF,
                                                   float* __restrict__ pbuf) {
  __shared__ alignas(16) __bf16 As[128 * 32];
  __shared__ alignas(16) __bf16 Bs[64 * 32];
  const int t = threadIdx.x, lane = t & 63;
  const int wr = t >> 7, wc = (t >> 6) & 1;
  const int kc = blockIdx.x, mt = blockIdx.y, pj = blockIdx.z;
  const __bf16* A = qkvv + (size_t)(pj ? 3 : 1) * 2048 * 8192;
  const __bf16* Bm = pj ? WF : WE;
  const int r0 = mt * 128;
  f32x4 acc[4][2] = {};
  const int r = t >> 2, c8 = (t & 3) * 8;
  for (int k0 = kc * 512; k0 < kc * 512 + 512; k0 += 32) {
#pragma unroll
    for (int i = 0; i < 2; ++i)
      gl2lds16(A + (size_t)(r0 + i * 64 + r) * 8192 + k0 + c8, As + i * 2048 + t * 8);
    gl2lds16(Bm + (size_t)r * 8192 + k0 + c8, Bs + t * 8);
    __syncthreads();
    bf16x8 af[4], bfr[2];
#pragma unroll
    for (int i = 0; i < 4; ++i)
      af[i] = *(const bf16x8*)(As + (wr * 64 + i * 16 + (lane & 15)) * 32 + (lane >> 4) * 8);
#pragma unroll
    for (int j = 0; j < 2; ++j)
      bfr[j] = *(const bf16x8*)(Bs + (wc * 32 + j * 16 + (lane & 15)) * 32 + (lane >> 4) * 8);
#pragma unroll
    for (int i = 0; i < 4; ++i)
#pragma unroll
      for (int j = 0; j < 2; ++j) acc[i][j] = MFMA(af[i], bfr[j], acc[i][j]);
    __syncthreads();
  }
  float* dst = pbuf + (size_t)((pj * 16 + kc) * 2048 + r0) * 64;
#pragma unroll
  for (int i = 0; i < 4; ++i)
#pragma unroll
    for (int j = 0; j < 2; ++j)
#pragma unroll
      for (int rr = 0; rr < 4; ++rr)
        dst[(wr * 64 + i * 16 + (lane >> 4) * 4 + rr) * 64 + wc * 32 + j * 16 + (lane & 15)] =
            acc[i][j][rr];
}

__global__ __launch_bounds__(256) void k_proj_reduce(const float* __restrict__ pbuf,
                                                     const __bf16* __restrict__ bE,
                                                     const __bf16* __restrict__ bF,
                                                     float* __restrict__ kproj,
                                                     float* __restrict__ vproj) {
  const int idx = blockIdx.x * 256 + threadIdx.x;  // [0, 262144)
  const int pj = idx >> 17, rp = idx & 131071, p = idx & 63;
  float s = (float)((pj ? bF : bE)[p]);
  const float* src = pbuf + (size_t)pj * 16 * 131072 + rp;
#pragma unroll
  for (int k = 0; k < 16; ++k) s += src[(size_t)k * 131072];
  (pj ? vproj : kproj)[rp] = s;
}

// ---------------- K4a: S[d,e] = q . k partials (K-split 8 x 4 waves) ----------
__global__ __launch_bounds__(256) void k_sca_part(const __bf16* __restrict__ qkvv,
                                                  float* __restrict__ spart) {
  const int bh = blockIdx.x, kc = blockIdx.y;
  const int t = threadIdx.x, lane = t & 63, w = t >> 6;
  const __bf16* qb = qkvv + (size_t)(bh * 32) * 8192;
  const __bf16* kb = qkvv + (size_t)(2048 + bh * 32) * 8192;
  f32x4 acc[2][2] = {};
  const int kbase = kc * 1024 + w * 256 + (lane >> 4) * 8;
#pragma unroll
  for (int ks = 0; ks < 256; ks += 32) {
    bf16x8 af[2], bfr[2];
#pragma unroll
    for (int i = 0; i < 2; ++i) {
      af[i] = *(const bf16x8*)(qb + (size_t)(i * 16 + (lane & 15)) * 8192 + kbase + ks);
      bfr[i] = *(const bf16x8*)(kb + (size_t)(i * 16 + (lane & 15)) * 8192 + kbase + ks);
    }
#pragma unroll
    for (int i = 0; i < 2; ++i)
#pragma unroll
      for (int j = 0; j < 2; ++j) acc[i][j] = MFMA(af[i], bfr[j], acc[i][j]);
  }
  float* dst = spart + (size_t)((bh * 8 + kc) * 4 + w) * 1024;
#pragma unroll
  for (int i = 0; i < 2; ++i)
#pragma unroll
    for (int j = 0; j < 2; ++j)
#pragma unroll
      for (int rr = 0; rr < 4; ++rr)
        dst[(i * 16 + (lane >> 4) * 4 + rr) * 32 + j * 16 + (lane & 15)] = acc[i][j][rr];
}

// ---------------- K4b: reduce partials, scale, softmax over e ----------------
__global__ __launch_bounds__(256) void k_sca_softmax(const float* __restrict__ spart,
                                                     const float* __restrict__ qinv,
                                                     const float* __restrict__ kinv,
                                                     const __bf16* __restrict__ temp1,
                                                     float* __restrict__ attn) {
  const int bh = blockIdx.x;
  __shared__ float S[1024];
  const int t = threadIdx.x;
  const float tmp = (float)temp1[bh & 7];
  for (int idx = t; idx < 1024; idx += 256) {
    float s = 0.f;
    const float* src = spart + (size_t)bh * 32768 + idx;
#pragma unroll
    for (int k = 0; k < 32; ++k) s += src[k * 1024];
    S[idx] = s * qinv[bh * 32 + (idx >> 5)] * kinv[bh * 32 + (idx & 31)] * tmp;
  }
  __syncthreads();
  const int lane = t & 63, w = t >> 6;
#pragma unroll
  for (int rr = 0; rr < 4; ++rr) {
    const int row = rr * 8 + w * 2 + (lane >> 5);
    const int e = lane & 31;
    float v = S[row * 32 + e];
    float m = v;
#pragma unroll
    for (int off = 16; off; off >>= 1) m = fmaxf(m, __shfl_xor(m, off, 32));
    const float ex = __expf(v - m);
    float sm = ex;
#pragma unroll
    for (int off = 16; off; off >>= 1) sm += __shfl_xor(sm, off, 32);
    attn[(size_t)bh * 1024 + row * 32 + e] = ex / sm;
  }
}

// ---------------- K4c: x_ca[b,n,h*32+d] = sum_e attn[d,e] * v_ca[e,n] --------
__global__ __launch_bounds__(256) void k_ca_apply(const __bf16* __restrict__ qkvv,
                                                  const float* __restrict__ attn,
                                                  __bf16* __restrict__ xca) {
  const int bh = blockIdx.x, b = bh >> 3, h = bh & 7;
  const int n = blockIdx.y * 256 + threadIdx.x;
  const __bf16* v = qkvv + (size_t)(4096 + bh * 32) * 8192 + n;
  float vv[32];
#pragma unroll
  for (int e = 0; e < 32; ++e) vv[e] = (float)v[(size_t)e * 8192];
  const float4* A4 = (const float4*)(attn + (size_t)bh * 1024);  // block-uniform reads
  __bf16* dst = xca + (size_t)(b * 8192 + n) * 256 + h * 32;
#pragma unroll
  for (int g = 0; g < 4; ++g) {
    bf16x8 pack;
#pragma unroll
    for (int dd = 0; dd < 8; ++dd) {
      const int d = g * 8 + dd;
      float s = 0.f;
#pragma unroll
      for (int i = 0; i < 8; ++i) {
        const float4 a = A4[d * 8 + i];
        s += a.x * vv[i * 4] + a.y * vv[i * 4 + 1] + a.z * vv[i * 4 + 2] + a.w * vv[i * 4 + 3];
      }
      pack[dd] = (__bf16)s;
    }
    *(bf16x8*)(dst + g * 8) = pack;
  }
}

// ---------------- K5: fused spatial (low-rank) attention ---------------------
// Per token: logits[p]=temp2*sum_d qn[d]*kproj[d,p]; softmax; out[d]=sum_p w*vproj[d,p].
// Writes x_sa in [b][h][d][n] layout (n contiguous).
__global__ __launch_bounds__(256) void k_spatial(const __bf16* __restrict__ qkvv,
                                                 const float* __restrict__ qinv,
                                                 const float* __restrict__ kproj,
                                                 const float* __restrict__ vproj,
                                                 const __bf16* __restrict__ temp2,
                                                 __bf16* __restrict__ xsa) {
  const int bh = blockIdx.x;
  const int n = blockIdx.y * 256 + threadIdx.x;
  const float tmp = (float)temp2[bh & 7];
  const __bf16* q = qkvv + (size_t)(bh * 32) * 8192 + n;
  float qn[32];
#pragma unroll
  for (int d = 0; d < 32; ++d) qn[d] = (float)q[(size_t)d * 8192] * qinv[bh * 32 + d] * tmp;
  const float4* kp = (const float4*)(kproj + (size_t)bh * 2048);  // block-uniform reads
  const float4* vp = (const float4*)(vproj + (size_t)bh * 2048);
  float4 lg[16];
#pragma unroll
  for (int i = 0; i < 16; ++i) lg[i] = make_float4(0.f, 0.f, 0.f, 0.f);
#pragma unroll
  for (int d = 0; d < 32; ++d) {
    const float qd = qn[d];
#pragma unroll
    for (int i = 0; i < 16; ++i) {
      const float4 k4 = kp[d * 16 + i];
      lg[i].x += qd * k4.x;
      lg[i].y += qd * k4.y;
      lg[i].z += qd * k4.z;
      lg[i].w += qd * k4.w;
    }
  }
  float m = lg[0].x;
#pragma unroll
  for (int i = 0; i < 16; ++i)
    m = fmaxf(m, fmaxf(fmaxf(lg[i].x, lg[i].y), fmaxf(lg[i].z, lg[i].w)));
  float sum = 0.f;
#pragma unroll
  for (int i = 0; i < 16; ++i) {
    lg[i].x = __expf(lg[i].x - m); sum += lg[i].x;
    lg[i].y = __expf(lg[i].y - m); sum += lg[i].y;
    lg[i].z = __expf(lg[i].z - m); sum += lg[i].z;
    lg[i].w = __expf(lg[i].w - m); sum += lg[i].w;
  }
  const float inv = 1.0f / sum;
#pragma unroll
  for (int d = 0; d < 32; ++d) {
    float o = 0.f;
#pragma unroll
    for (int i = 0; i < 16; ++i) {
      const float4 v4 = vp[d * 16 + i];
      o += lg[i].x * v4.x + lg[i].y * v4.y + lg[i].z * v4.z + lg[i].w * v4.w;
    }
    xsa[(size_t)(bh * 32 + d) * 8192 + n] = (__bf16)(o * inv);
  }
}

// ---------------- K6: output projections (both halves) -----------------------
// br=0: out[b,n',0:128]   = xsa_mat[b,n',:] . Wo1^T + bo1  (scrambled row mapping)
// br=1: out[b,n',128:256] = xca[b,n',:] . Wo2^T + bo2
__global__ __launch_bounds__(256) void k_out(const __bf16* __restrict__ xsa,
                                             const __bf16* __restrict__ xca,
                                             const __bf16* __restrict__ Wo1,
                                             const __bf16* __restrict__ bo1,
                                             const __bf16* __restrict__ Wo2,
                                             const __bf16* __restrict__ bo2,
                                             void* __restrict__ outv,
                                             const int* __restrict__ flag) {
  __shared__ alignas(16) __bf16 As[128 * 32];
  __shared__ alignas(16) __bf16 Bs[128 * 32];
  const int t = threadIdx.x, lane = t & 63;
  const int wr = t >> 7, wc = (t >> 6) & 1;
  const int nt = blockIdx.x, b = blockIdx.y, br = blockIdx.z;
  const int isf32 = *flag;
  const __bf16* Wo = br ? Wo2 : Wo1;
  const __bf16* bo = br ? bo2 : bo1;
  f32x4 acc[4][4] = {};
  const int r = t >> 2, c8 = (t & 3) * 8;
  for (int k0 = 0; k0 < 256; k0 += 32) {
#pragma unroll
    for (int i = 0; i < 2; ++i) {
      const int row = nt * 128 + i * 64 + r;
      const __bf16* ga;
      if (br == 0) {
        // x_sa_mat[b,row,c] = xsa[b][(row>>5)&7][row>>8][(row&31)*256 + c]
        ga = xsa + (size_t)((b * 8 + ((row >> 5) & 7)) * 32 + (row >> 8)) * 8192 +
             (row & 31) * 256 + k0 + c8;
      } else {
        ga = xca + (size_t)(b * 8192 + row) * 256 + k0 + c8;
      }
      gl2lds16(ga, As + i * 2048 + t * 8);
      gl2lds16(Wo + (size_t)(i * 64 + r) * 256 + k0 + c8, Bs + i * 2048 + t * 8);
    }
    __syncthreads();
    bf16x8 af[4], bfr[4];
#pragma unroll
    for (int i = 0; i < 4; ++i) {
      af[i] = *(const bf16x8*)(As + (wr * 64 + i * 16 + (lane & 15)) * 32 + (lane >> 4) * 8);
      bfr[i] = *(const bf16x8*)(Bs + (wc * 64 + i * 16 + (lane & 15)) * 32 + (lane >> 4) * 8);
    }
#pragma unroll
    for (int i = 0; i < 4; ++i)
#pragma unroll
      for (int j = 0; j < 4; ++j) acc[i][j] = MFMA(af[i], bfr[j], acc[i][j]);
    __syncthreads();
  }
  float bias[4];
#pragma unroll
  for (int j = 0; j < 4; ++j) bias[j] = (float)bo[wc * 64 + j * 16 + (lane & 15)];
#pragma unroll
  for (int i = 0; i < 4; ++i) {
#pragma unroll
    for (int j = 0; j < 4; ++j) {
      const int col = wc * 64 + j * 16 + (lane & 15);
#pragma unroll
      for (int rr = 0; rr < 4; ++rr) {
        const int row = nt * 128 + wr * 64 + i * 16 + (lane >> 4) * 4 + rr;
        const float val = acc[i][j][rr] + bias[j];
        const size_t oi = (size_t)(b * 8192 + row) * 256 + br * 128 + col;
        if (isf32) ((float*)outv)[oi] = val;
        else ((__bf16*)outv)[oi] = (__bf16)val;
      }
    }
  }
}

extern "C" void kernel_launch(void* const* d_in, const int* in_sizes, int n_in,
                              void* d_out, int out_size, void* d_ws, size_t ws_size,
                              hipStream_t stream) {
  char* ws = (char*)d_ws;
  // Workspace layout (total ~205.4 MB; aliasing noted):
  __bf16* qkvv  = (__bf16*)(ws);                    // 134,217,728 B
  __bf16* cinx  = (__bf16*)(ws + 134217728ull);     //  33,554,432 B (region A)
  __bf16* xca   = (__bf16*)(ws + 134217728ull);     //  alias A (cinx dead after k_qkvv)
  float*  pbuf  = (float*)(ws + 167772160ull);      //  16,777,216 B (region B)
  float*  spart = (float*)(ws + 184549376ull);      //   8,388,608 B (region B + 16M)
  __bf16* xsa   = (__bf16*)(ws + 167772160ull);     //  alias B (pbuf/spart dead by then)
  float*  kproj = (float*)(ws + 201326592ull);      //     524,288 B
  float*  vproj = (float*)(ws + 201850880ull);      //     524,288 B
  float*  qinv  = (float*)(ws + 202375168ull);      //       8,192 B
  float*  kinv  = (float*)(ws + 202383360ull);      //       8,192 B
  float*  attn  = (float*)(ws + 202391552ull);      //     262,144 B
  __bf16* cw    = (__bf16*)(ws + 202653696ull);     //   2,753,536 B (canonical weights)
  int*    flag  = (int*)(ws + 205407232ull);        //           4 B

  __bf16* cWq  = cw;
  __bf16* cWE  = cw + 262144;
  __bf16* cbE  = cw + 786432;
  __bf16* cWF  = cw + 786496;
  __bf16* cbF  = cw + 1310784;
  __bf16* cWo1 = cw + 1310848;
  __bf16* cbo1 = cw + 1343616;
  __bf16* cWo2 = cw + 1343744;
  __bf16* cbo2 = cw + 1376512;
  __bf16* ct1  = cw + 1376640;
  __bf16* ct2  = cw + 1376648;

  k_detect<<<1, 256, 0, stream>>>((const unsigned short*)d_in[0], flag);
  k_convert_x<<<8192, 256, 0, stream>>>(d_in[0], cinx, flag);
  k_convert_w<<<673, 256, 0, stream>>>(d_in[1], d_in[2], d_in[3], d_in[4], d_in[5],
                                       d_in[6], d_in[7], d_in[8], d_in[9], d_in[10],
                                       d_in[11], cw, flag);
  k_qkvv<<<dim3(512, 8), 256, 0, stream>>>(cinx, cWq, qkvv);
  k_norms<<<dim3(2048, 2), 256, 0, stream>>>(qkvv, qinv, kinv);
  k_proj_part<<<dim3(16, 16, 2), 256, 0, stream>>>(qkvv, cWE, cWF, pbuf);
  k_proj_reduce<<<dim3(1024), 256, 0, stream>>>(pbuf, cbE, cbF, kproj, vproj);
  k_sca_part<<<dim3(64, 8), 256, 0, stream>>>(qkvv, spart);
  k_sca_softmax<<<dim3(64), 256, 0, stream>>>(spart, qinv, kinv, ct1, attn);
  k_ca_apply<<<dim3(64, 32), 256, 0, stream>>>(qkvv, attn, xca);
  k_spatial<<<dim3(64, 32), 256, 0, stream>>>(qkvv, qinv, kproj, vproj, ct2, xsa);
  k_out<<<dim3(64, 8, 2), 256, 0, stream>>>(xsa, xca, cWo1, cbo1, cWo2, cbo2, d_out, flag);
}

// Round 3
// 332.204 us; speedup vs baseline: 1.4416x; 1.4416x over previous
//
#include <hip/hip_runtime.h>
#include <hip/hip_bf16.h>
#include <stdint.h>

// Problem: B=8, N=8192, C=256, H=8, D=32, P=64, F=4C=1024
// qkvv layout: [part(4)][b(8)][h*32+d(256)][n(8192)] bf16, n contiguous.
// Inputs detected as fp32-or-bf16; canonicalized to bf16 workspace buffers.

typedef __attribute__((ext_vector_type(8))) __bf16 bf16x8;
typedef __attribute__((ext_vector_type(4))) __bf16 bf16x4;
typedef __attribute__((ext_vector_type(4))) float f32x4;

#define MFMA(a, b, c) __builtin_amdgcn_mfma_f32_16x16x32_bf16((a), (b), (c), 0, 0, 0)

__device__ __forceinline__ void gl2lds16(const __bf16* g, __bf16* l) {
  __builtin_amdgcn_global_load_lds(
      (const __attribute__((address_space(1))) void*)(const void*)g,
      (__attribute__((address_space(3))) void*)(void*)l, 16, 0, 0);
}

// ---------------- K0a: dtype detection --------------------------------------
__global__ __launch_bounds__(256) void k_detect(const unsigned short* __restrict__ xr,
                                                int* __restrict__ flag) {
  __shared__ int cnt;
  if (threadIdx.x == 0) cnt = 0;
  __syncthreads();
  int c = 0;
  for (int i = threadIdx.x; i < 8192; i += 256) {
    const int e = (xr[i] >> 7) & 0xFF;
    c += (e >= 0xC0) ? 1 : 0;
  }
  atomicAdd(&cnt, c);
  __syncthreads();
  if (threadIdx.x == 0) *flag = (cnt > 100) ? 1 : 0;
}

// ---------------- K0b: canonicalize x ----------------------------------------
__global__ __launch_bounds__(256) void k_convert_x(const void* __restrict__ src,
                                                   __bf16* __restrict__ dst,
                                                   const int* __restrict__ flag) {
  const int i = (blockIdx.x * 256 + threadIdx.x) * 8;  // < 16777216
  if (*flag) {
    const float* s = (const float*)src;
    bf16x8 v;
#pragma unroll
    for (int j = 0; j < 8; ++j) v[j] = (__bf16)s[i + j];
    *(bf16x8*)(dst + i) = v;
  } else {
    *(bf16x8*)(dst + i) = *(const bf16x8*)((const __bf16*)src + i);
  }
}

// ---------------- K0c: canonicalize the 11 weight/bias/temp inputs -----------
__global__ __launch_bounds__(256) void k_convert_w(
    const void* s0, const void* s1, const void* s2, const void* s3, const void* s4,
    const void* s5, const void* s6, const void* s7, const void* s8, const void* s9,
    const void* s10, __bf16* __restrict__ cw, const int* __restrict__ flag) {
  const int i = (blockIdx.x * 256 + threadIdx.x) * 8;
  if (i >= 1376656) return;
  const void* s;
  int base;
  if (i < 262144)        { s = s0;  base = 0; }
  else if (i < 786432)   { s = s1;  base = 262144; }
  else if (i < 786496)   { s = s2;  base = 786432; }
  else if (i < 1310784)  { s = s3;  base = 786496; }
  else if (i < 1310848)  { s = s4;  base = 1310784; }
  else if (i < 1343616)  { s = s5;  base = 1310848; }
  else if (i < 1343744)  { s = s6;  base = 1343616; }
  else if (i < 1376512)  { s = s7;  base = 1343744; }
  else if (i < 1376640)  { s = s8;  base = 1376512; }
  else if (i < 1376648)  { s = s9;  base = 1376640; }
  else                   { s = s10; base = 1376648; }
  const int li = i - base;
  if (*flag) {
    const float* sf = (const float*)s;
#pragma unroll
    for (int j = 0; j < 8; ++j) cw[i + j] = (__bf16)sf[li + j];
  } else {
    const __bf16* sb = (const __bf16*)s;
#pragma unroll
    for (int j = 0; j < 8; ++j) cw[i + j] = sb[li + j];
  }
}

// ---------------- K1: qkvv = x @ Wqkvv^T, stored transposed ------------------
__global__ __launch_bounds__(256) void k_qkvv(const __bf16* __restrict__ x,
                                              const __bf16* __restrict__ Wq,
                                              __bf16* __restrict__ qkvv) {
  __shared__ alignas(16) __bf16 As[128 * 32];
  __shared__ alignas(16) __bf16 Bs[128 * 32];
  const int t = threadIdx.x, lane = t & 63;
  const int wr = t >> 7, wc = (t >> 6) & 1;
  const int f0 = blockIdx.y * 128;
  const int t0 = blockIdx.x * 128;
  f32x4 acc[4][4] = {};
  const int r = t >> 2, c8 = (t & 3) * 8;
  for (int k0 = 0; k0 < 256; k0 += 32) {
#pragma unroll
    for (int i = 0; i < 2; ++i) {
      gl2lds16(Wq + (size_t)(f0 + i * 64 + r) * 256 + k0 + c8, As + i * 2048 + t * 8);
      gl2lds16(x + (size_t)(t0 + i * 64 + r) * 256 + k0 + c8, Bs + i * 2048 + t * 8);
    }
    __syncthreads();
    bf16x8 af[4], bfr[4];
#pragma unroll
    for (int i = 0; i < 4; ++i) {
      af[i] = *(const bf16x8*)(As + (wr * 64 + i * 16 + (lane & 15)) * 32 + (lane >> 4) * 8);
      bfr[i] = *(const bf16x8*)(Bs + (wc * 64 + i * 16 + (lane & 15)) * 32 + (lane >> 4) * 8);
    }
#pragma unroll
    for (int i = 0; i < 4; ++i)
#pragma unroll
      for (int j = 0; j < 4; ++j) acc[i][j] = MFMA(af[i], bfr[j], acc[i][j]);
    __syncthreads();
  }
  const int b = t0 >> 13;
#pragma unroll
  for (int i = 0; i < 4; ++i) {
#pragma unroll
    for (int j = 0; j < 4; ++j) {
      const int tok = t0 + wc * 64 + j * 16 + (lane & 15);
      const int n = tok & 8191;
#pragma unroll
      for (int rr = 0; rr < 4; ++rr) {
        const int f = f0 + wr * 64 + i * 16 + (lane >> 4) * 4 + rr;
        qkvv[(size_t)(((f >> 8) * 8 + b) * 256 + (f & 255)) * 8192 + n] = (__bf16)acc[i][j][rr];
      }
    }
  }
}

// ---------------- K2: inverse L2 norms over n for q (part0) and k (part1) ----
__global__ __launch_bounds__(256) void k_norms(const __bf16* __restrict__ qkvv,
                                               float* __restrict__ qinv,
                                               float* __restrict__ kinv) {
  const int row = blockIdx.x, which = blockIdx.y;
  const __bf16* p = qkvv + (size_t)(which * 2048 + row) * 8192;
  float s = 0.f;
  for (int i = threadIdx.x; i < 8192; i += 256) {
    const float v = (float)p[i];
    s += v * v;
  }
#pragma unroll
  for (int off = 32; off; off >>= 1) s += __shfl_down(s, off, 64);
  __shared__ float red[4];
  if ((threadIdx.x & 63) == 0) red[threadIdx.x >> 6] = s;
  __syncthreads();
  if (threadIdx.x == 0) {
    const float tot = red[0] + red[1] + red[2] + red[3];
    const float inv = 1.0f / fmaxf(sqrtf(tot), 1e-12f);
    (which ? kinv : qinv)[row] = inv;
  }
}

// ---------------- K3: k_proj / v_proj partial GEMMs (K-split) ----------------
__global__ __launch_bounds__(256) void k_proj_part(const __bf16* __restrict__ qkvv,
                                                   const __bf16* __restrict__ WE,
                                                   const __bf16* __restrict__ WF,
                                                   float* __restrict__ pbuf) {
  __shared__ alignas(16) __bf16 As[128 * 32];
  __shared__ alignas(16) __bf16 Bs[64 * 32];
  const int t = threadIdx.x, lane = t & 63;
  const int wr = t >> 7, wc = (t >> 6) & 1;
  const int kc = blockIdx.x, mt = blockIdx.y, pj = blockIdx.z;
  const __bf16* A = qkvv + (size_t)(pj ? 3 : 1) * 2048 * 8192;
  const __bf16* Bm = pj ? WF : WE;
  const int r0 = mt * 128;
  f32x4 acc[4][2] = {};
  const int r = t >> 2, c8 = (t & 3) * 8;
  for (int k0 = kc * 512; k0 < kc * 512 + 512; k0 += 32) {
#pragma unroll
    for (int i = 0; i < 2; ++i)
      gl2lds16(A + (size_t)(r0 + i * 64 + r) * 8192 + k0 + c8, As + i * 2048 + t * 8);
    gl2lds16(Bm + (size_t)r * 8192 + k0 + c8, Bs + t * 8);
    __syncthreads();
    bf16x8 af[4], bfr[2];
#pragma unroll
    for (int i = 0; i < 4; ++i)
      af[i] = *(const bf16x8*)(As + (wr * 64 + i * 16 + (lane & 15)) * 32 + (lane >> 4) * 8);
#pragma unroll
    for (int j = 0; j < 2; ++j)
      bfr[j] = *(const bf16x8*)(Bs + (wc * 32 + j * 16 + (lane & 15)) * 32 + (lane >> 4) * 8);
#pragma unroll
    for (int i = 0; i < 4; ++i)
#pragma unroll
      for (int j = 0; j < 2; ++j) acc[i][j] = MFMA(af[i], bfr[j], acc[i][j]);
    __syncthreads();
  }
  float* dst = pbuf + (size_t)((pj * 16 + kc) * 2048 + r0) * 64;
#pragma unroll
  for (int i = 0; i < 4; ++i)
#pragma unroll
    for (int j = 0; j < 2; ++j)
#pragma unroll
      for (int rr = 0; rr < 4; ++rr)
        dst[(wr * 64 + i * 16 + (lane >> 4) * 4 + rr) * 64 + wc * 32 + j * 16 + (lane & 15)] =
            acc[i][j][rr];
}

// ---------------- K3b: reduce + bias; emit bf16 MFMA-operand copies ----------
// kprojT[bh][p][d] = (kproj + bE) * qinv[bh,d] * temp2[h]   (A-operand for logits GEMM)
// vprojb[bh][d][p] = (vproj + bF)                            (A-operand for PV GEMM)
__global__ __launch_bounds__(256) void k_proj_reduce(const float* __restrict__ pbuf,
                                                     const __bf16* __restrict__ bE,
                                                     const __bf16* __restrict__ bF,
                                                     const float* __restrict__ qinv,
                                                     const __bf16* __restrict__ t2,
                                                     __bf16* __restrict__ kprojT,
                                                     __bf16* __restrict__ vprojb) {
  const int idx = blockIdx.x * 256 + threadIdx.x;  // [0, 262144)
  const int pj = idx >> 17, rp = idx & 131071, p = idx & 63;
  const int row = rp >> 6, bh = row >> 5, d = row & 31, h = bh & 7;
  float s = (float)((pj ? bF : bE)[p]);
  const float* src = pbuf + (size_t)pj * 16 * 131072 + rp;
#pragma unroll
  for (int k = 0; k < 16; ++k) s += src[(size_t)k * 131072];
  if (pj == 0)
    kprojT[bh * 2048 + p * 32 + d] = (__bf16)(s * qinv[row] * (float)t2[h]);
  else
    vprojb[bh * 2048 + d * 64 + p] = (__bf16)s;
}

// ---------------- K4a: S[d,e] = q . k partials (K-split 8 x 4 waves) ---------
__global__ __launch_bounds__(256) void k_sca_part(const __bf16* __restrict__ qkvv,
                                                  float* __restrict__ spart) {
  const int bh = blockIdx.x, kc = blockIdx.y;
  const int t = threadIdx.x, lane = t & 63, w = t >> 6;
  const __bf16* qb = qkvv + (size_t)(bh * 32) * 8192;
  const __bf16* kb = qkvv + (size_t)(2048 + bh * 32) * 8192;
  f32x4 acc[2][2] = {};
  const int kbase = kc * 1024 + w * 256 + (lane >> 4) * 8;
#pragma unroll
  for (int ks = 0; ks < 256; ks += 32) {
    bf16x8 af[2], bfr[2];
#pragma unroll
    for (int i = 0; i < 2; ++i) {
      af[i] = *(const bf16x8*)(qb + (size_t)(i * 16 + (lane & 15)) * 8192 + kbase + ks);
      bfr[i] = *(const bf16x8*)(kb + (size_t)(i * 16 + (lane & 15)) * 8192 + kbase + ks);
    }
#pragma unroll
    for (int i = 0; i < 2; ++i)
#pragma unroll
      for (int j = 0; j < 2; ++j) acc[i][j] = MFMA(af[i], bfr[j], acc[i][j]);
  }
  float* dst = spart + (size_t)((bh * 8 + kc) * 4 + w) * 1024;
#pragma unroll
  for (int i = 0; i < 2; ++i)
#pragma unroll
    for (int j = 0; j < 2; ++j)
#pragma unroll
      for (int rr = 0; rr < 4; ++rr)
        dst[(i * 16 + (lane >> 4) * 4 + rr) * 32 + j * 16 + (lane & 15)] = acc[i][j][rr];
}

// ---------------- K4b: reduce, scale, softmax over e; emit bf16 attn [d][e] --
__global__ __launch_bounds__(256) void k_sca_softmax(const float* __restrict__ spart,
                                                     const float* __restrict__ qinv,
                                                     const float* __restrict__ kinv,
                                                     const __bf16* __restrict__ temp1,
                                                     __bf16* __restrict__ attnb) {
  const int bh = blockIdx.x;
  __shared__ float S[1024];
  const int t = threadIdx.x;
  const float tmp = (float)temp1[bh & 7];
  for (int idx = t; idx < 1024; idx += 256) {
    float s = 0.f;
    const float* src = spart + (size_t)bh * 32768 + idx;
#pragma unroll
    for (int k = 0; k < 32; ++k) s += src[k * 1024];
    S[idx] = s * qinv[bh * 32 + (idx >> 5)] * kinv[bh * 32 + (idx & 31)] * tmp;
  }
  __syncthreads();
  const int lane = t & 63, w = t >> 6;
#pragma unroll
  for (int rr = 0; rr < 4; ++rr) {
    const int row = rr * 8 + w * 2 + (lane >> 5);
    const int e = lane & 31;
    float v = S[row * 32 + e];
    float m = v;
#pragma unroll
    for (int off = 16; off; off >>= 1) m = fmaxf(m, __shfl_xor(m, off, 32));
    const float ex = __expf(v - m);
    float sm = ex;
#pragma unroll
    for (int off = 16; off; off >>= 1) sm += __shfl_xor(sm, off, 32);
    attnb[(size_t)bh * 1024 + row * 32 + e] = (__bf16)(ex / sm);
  }
}

// ---------------- K4c: channel-attn apply via MFMA ---------------------------
// x_ca[d][tok] = sum_e attn[d][e] * v_ca[e][tok]; M=d(32), N=16 tok/wave, K=e(32).
__global__ __launch_bounds__(256) void k_ca_mfma(const __bf16* __restrict__ qkvv,
                                                 const __bf16* __restrict__ attnb,
                                                 __bf16* __restrict__ xca) {
  const int t = threadIdx.x, lane = t & 63, w = t >> 6;
  const int l15 = lane & 15, g = lane >> 4;
  const int bh = blockIdx.y, b = bh >> 3, h = bh & 7;
  const __bf16* vb = qkvv + (size_t)(4096 + bh * 32) * 8192;
  bf16x8 aa[2];
#pragma unroll
  for (int mi = 0; mi < 2; ++mi)
    aa[mi] = *(const bf16x8*)(attnb + bh * 1024 + (mi * 16 + l15) * 32 + g * 8);
#pragma unroll
  for (int it = 0; it < 4; ++it) {
    const int n = blockIdx.x * 256 + it * 64 + w * 16 + l15;
    union { bf16x8 v; unsigned short u[8]; } bq;
#pragma unroll
    for (int j = 0; j < 8; ++j)
      bq.u[j] = *(const unsigned short*)(vb + (size_t)(g * 8 + j) * 8192 + n);
    f32x4 o[2] = {};
#pragma unroll
    for (int mi = 0; mi < 2; ++mi) o[mi] = MFMA(aa[mi], bq.v, o[mi]);
#pragma unroll
    for (int mi = 0; mi < 2; ++mi) {
      bf16x4 p4;
#pragma unroll
      for (int rr = 0; rr < 4; ++rr) p4[rr] = (__bf16)o[mi][rr];
      *(bf16x4*)(xca + (size_t)(b * 8192 + n) * 256 + h * 32 + mi * 16 + g * 4) = p4;
    }
  }
}

// ---------------- K5: spatial (low-rank) attention via MFMA ------------------
// Logits: St[p][tok] = kprojT(64x32) x q-frag; softmax over p (cross-lane);
// PV: x_sa[d][tok] = vprojb(32x64) x P-frag (LDS round-trip). 16 tok/wave/iter.
__global__ __launch_bounds__(256) void k_sa_mfma(const __bf16* __restrict__ qkvv,
                                                 const __bf16* __restrict__ kprojT,
                                                 const __bf16* __restrict__ vprojb,
                                                 __bf16* __restrict__ xsa) {
  __shared__ __bf16 P[4][16 * 72];  // per-wave region, 72-elem padded rows
  const int t = threadIdx.x, lane = t & 63, w = t >> 6;
  const int l15 = lane & 15, g = lane >> 4;
  const int bh = blockIdx.y;
  const __bf16* qb = qkvv + (size_t)(bh * 32) * 8192;
  bf16x8 ka[4], va[2][2];
#pragma unroll
  for (int tile = 0; tile < 4; ++tile)
    ka[tile] = *(const bf16x8*)(kprojT + bh * 2048 + (tile * 16 + l15) * 32 + g * 8);
#pragma unroll
  for (int mi = 0; mi < 2; ++mi)
#pragma unroll
    for (int kh = 0; kh < 2; ++kh)
      va[mi][kh] = *(const bf16x8*)(vprojb + bh * 2048 + (mi * 16 + l15) * 64 + kh * 32 + g * 8);
  __bf16* Pw = &P[w][0];
#pragma unroll
  for (int it = 0; it < 4; ++it) {
    const int n0 = blockIdx.x * 256 + it * 64 + w * 16;
    union { bf16x8 v; unsigned short u[8]; } bq;
#pragma unroll
    for (int j = 0; j < 8; ++j)
      bq.u[j] = *(const unsigned short*)(qb + (size_t)(g * 8 + j) * 8192 + n0 + l15);
    f32x4 st[4];
#pragma unroll
    for (int tile = 0; tile < 4; ++tile) {
      f32x4 z = {};
      st[tile] = MFMA(ka[tile], bq.v, z);
    }
    // softmax over p=64 for this lane's token (lanes l, l^16, l^32, l^48)
    float m = st[0][0];
#pragma unroll
    for (int tile = 0; tile < 4; ++tile)
#pragma unroll
      for (int rr = 0; rr < 4; ++rr) m = fmaxf(m, st[tile][rr]);
    m = fmaxf(m, __shfl_xor(m, 16, 64));
    m = fmaxf(m, __shfl_xor(m, 32, 64));
    float sum = 0.f;
#pragma unroll
    for (int tile = 0; tile < 4; ++tile) {
      bf16x4 p4;
#pragma unroll
      for (int rr = 0; rr < 4; ++rr) {
        const float ex = __expf(st[tile][rr] - m);
        sum += ex;
        p4[rr] = (__bf16)ex;
      }
      *(bf16x4*)(Pw + l15 * 72 + tile * 16 + g * 4) = p4;
    }
    sum += __shfl_xor(sum, 16, 64);
    sum += __shfl_xor(sum, 32, 64);
    const float inv = 1.0f / sum;
    f32x4 o[2] = {};
#pragma unroll
    for (int kh = 0; kh < 2; ++kh) {
      const bf16x8 pf = *(const bf16x8*)(Pw + l15 * 72 + kh * 32 + g * 8);
#pragma unroll
      for (int mi = 0; mi < 2; ++mi) o[mi] = MFMA(va[mi][kh], pf, o[mi]);
    }
#pragma unroll
    for (int mi = 0; mi < 2; ++mi)
#pragma unroll
      for (int rr = 0; rr < 4; ++rr) {
        const int d = mi * 16 + g * 4 + rr;
        xsa[(size_t)(bh * 32 + d) * 8192 + n0 + l15] = (__bf16)(o[mi][rr] * inv);
      }
  }
}

// ---------------- K6: output projections (both halves) -----------------------
__global__ __launch_bounds__(256) void k_out(const __bf16* __restrict__ xsa,
                                             const __bf16* __restrict__ xca,
                                             const __bf16* __restrict__ Wo1,
                                             const __bf16* __restrict__ bo1,
                                             const __bf16* __restrict__ Wo2,
                                             const __bf16* __restrict__ bo2,
                                             void* __restrict__ outv,
                                             const int* __restrict__ flag) {
  __shared__ alignas(16) __bf16 As[128 * 32];
  __shared__ alignas(16) __bf16 Bs[128 * 32];
  const int t = threadIdx.x, lane = t & 63;
  const int wr = t >> 7, wc = (t >> 6) & 1;
  const int nt = blockIdx.x, b = blockIdx.y, br = blockIdx.z;
  const int isf32 = *flag;
  const __bf16* Wo = br ? Wo2 : Wo1;
  const __bf16* bo = br ? bo2 : bo1;
  f32x4 acc[4][4] = {};
  const int r = t >> 2, c8 = (t & 3) * 8;
  for (int k0 = 0; k0 < 256; k0 += 32) {
#pragma unroll
    for (int i = 0; i < 2; ++i) {
      const int row = nt * 128 + i * 64 + r;
      const __bf16* ga;
      if (br == 0) {
        ga = xsa + (size_t)((b * 8 + ((row >> 5) & 7)) * 32 + (row >> 8)) * 8192 +
             (row & 31) * 256 + k0 + c8;
      } else {
        ga = xca + (size_t)(b * 8192 + row) * 256 + k0 + c8;
      }
      gl2lds16(ga, As + i * 2048 + t * 8);
      gl2lds16(Wo + (size_t)(i * 64 + r) * 256 + k0 + c8, Bs + i * 2048 + t * 8);
    }
    __syncthreads();
    bf16x8 af[4], bfr[4];
#pragma unroll
    for (int i = 0; i < 4; ++i) {
      af[i] = *(const bf16x8*)(As + (wr * 64 + i * 16 + (lane & 15)) * 32 + (lane >> 4) * 8);
      bfr[i] = *(const bf16x8*)(Bs + (wc * 64 + i * 16 + (lane & 15)) * 32 + (lane >> 4) * 8);
    }
#pragma unroll
    for (int i = 0; i < 4; ++i)
#pragma unroll
      for (int j = 0; j < 4; ++j) acc[i][j] = MFMA(af[i], bfr[j], acc[i][j]);
    __syncthreads();
  }
  float bias[4];
#pragma unroll
  for (int j = 0; j < 4; ++j) bias[j] = (float)bo[wc * 64 + j * 16 + (lane & 15)];
#pragma unroll
  for (int i = 0; i < 4; ++i) {
#pragma unroll
    for (int j = 0; j < 4; ++j) {
      const int col = wc * 64 + j * 16 + (lane & 15);
#pragma unroll
      for (int rr = 0; rr < 4; ++rr) {
        const int row = nt * 128 + wr * 64 + i * 16 + (lane >> 4) * 4 + rr;
        const float val = acc[i][j][rr] + bias[j];
        const size_t oi = (size_t)(b * 8192 + row) * 256 + br * 128 + col;
        if (isf32) ((float*)outv)[oi] = val;
        else ((__bf16*)outv)[oi] = (__bf16)val;
      }
    }
  }
}

extern "C" void kernel_launch(void* const* d_in, const int* in_sizes, int n_in,
                              void* d_out, int out_size, void* d_ws, size_t ws_size,
                              hipStream_t stream) {
  char* ws = (char*)d_ws;
  __bf16* qkvv   = (__bf16*)(ws);                    // 134,217,728 B
  __bf16* cinx   = (__bf16*)(ws + 134217728ull);     //  32 MB (region A)
  __bf16* xca    = (__bf16*)(ws + 134217728ull);     //  alias A (cinx dead after k_qkvv)
  float*  pbuf   = (float*)(ws + 167772160ull);      //  16 MB (region B)
  float*  spart  = (float*)(ws + 184549376ull);      //   8 MB (region B + 16M)
  __bf16* xsa    = (__bf16*)(ws + 167772160ull);     //  alias B (pbuf/spart dead by then)
  __bf16* kprojT = (__bf16*)(ws + 201326592ull);     //  262,144 B
  __bf16* vprojb = (__bf16*)(ws + 201588736ull);     //  262,144 B
  float*  qinv   = (float*)(ws + 201850880ull);      //    8,192 B
  float*  kinv   = (float*)(ws + 201859072ull);      //    8,192 B
  __bf16* attnb  = (__bf16*)(ws + 201867264ull);     //  131,072 B
  __bf16* cw     = (__bf16*)(ws + 201998336ull);     //  2,753,536 B
  int*    flag   = (int*)(ws + 204751872ull);        //          4 B

  __bf16* cWq  = cw;
  __bf16* cWE  = cw + 262144;
  __bf16* cbE  = cw + 786432;
  __bf16* cWF  = cw + 786496;
  __bf16* cbF  = cw + 1310784;
  __bf16* cWo1 = cw + 1310848;
  __bf16* cbo1 = cw + 1343616;
  __bf16* cWo2 = cw + 1343744;
  __bf16* cbo2 = cw + 1376512;
  __bf16* ct1  = cw + 1376640;
  __bf16* ct2  = cw + 1376648;

  k_detect<<<1, 256, 0, stream>>>((const unsigned short*)d_in[0], flag);
  k_convert_x<<<8192, 256, 0, stream>>>(d_in[0], cinx, flag);
  k_convert_w<<<673, 256, 0, stream>>>(d_in[1], d_in[2], d_in[3], d_in[4], d_in[5],
                                       d_in[6], d_in[7], d_in[8], d_in[9], d_in[10],
                                       d_in[11], cw, flag);
  k_qkvv<<<dim3(512, 8), 256, 0, stream>>>(cinx, cWq, qkvv);
  k_norms<<<dim3(2048, 2), 256, 0, stream>>>(qkvv, qinv, kinv);
  k_proj_part<<<dim3(16, 16, 2), 256, 0, stream>>>(qkvv, cWE, cWF, pbuf);
  k_proj_reduce<<<dim3(1024), 256, 0, stream>>>(pbuf, cbE, cbF, qinv, ct2, kprojT, vprojb);
  k_sca_part<<<dim3(64, 8), 256, 0, stream>>>(qkvv, spart);
  k_sca_softmax<<<dim3(64), 256, 0, stream>>>(spart, qinv, kinv, ct1, attnb);
  k_ca_mfma<<<dim3(32, 64), 256, 0, stream>>>(qkvv, attnb, xca);
  k_sa_mfma<<<dim3(32, 64), 256, 0, stream>>>(qkvv, kprojT, vprojb, xsa);
  k_out<<<dim3(64, 8, 2), 256, 0, stream>>>(xsa, xca, cWo1, cbo1, cWo2, cbo2, d_out, flag);
}

// Round 4
// 329.975 us; speedup vs baseline: 1.4514x; 1.0068x over previous
//
#include <hip/hip_runtime.h>
#include <hip/hip_bf16.h>
#include <stdint.h>

// Problem: B=8, N=8192, C=256, H=8, D=32, P=64, F=4C=1024
// qkvv layout: [part(4)][b(8)][h*32+d(256)][n(8192)] bf16, n contiguous.
// Inputs self-detected as fp32-or-bf16; canonicalized to bf16 workspace buffers.
// LDS tiles use XOR chunk swizzle (chunk = g ^ ((row>>1)&3)) on both the
// global_load_lds staging side and the ds_read_b128 fragment side: 2-way bank
// aliasing (free) instead of 8-way.

typedef __attribute__((ext_vector_type(8))) __bf16 bf16x8;
typedef __attribute__((ext_vector_type(4))) __bf16 bf16x4;
typedef __attribute__((ext_vector_type(4))) float f32x4;

#define MFMA(a, b, c) __builtin_amdgcn_mfma_f32_16x16x32_bf16((a), (b), (c), 0, 0, 0)

__device__ __forceinline__ void gl2lds16(const __bf16* g, __bf16* l) {
  __builtin_amdgcn_global_load_lds(
      (const __attribute__((address_space(1))) void*)(const void*)g,
      (__attribute__((address_space(3))) void*)(void*)l, 16, 0, 0);
}

// Self-detect: sample x's first 64 dwords (uniform scalar loads). fp32 data's
// low halfwords are mantissa bytes -> exponent field >= 0xC0 w.p. ~1/4; real
// bf16 N(0,1)-scale data never has exp >= 0xC0 (would be >= 2^65).
__device__ __forceinline__ int detect_f32(const unsigned int* __restrict__ xw) {
  int c = 0;
#pragma unroll
  for (int i = 0; i < 64; ++i) {
    const unsigned int u = xw[i];
    c += (((u >> 7) & 0xFF) >= 0xC0) ? 1 : 0;
    c += (((u >> 23) & 0xFF) >= 0xC0) ? 1 : 0;
  }
  return c > 8;
}

// ---------------- K0a: canonicalize x (+ zero qsum/ksum via block 0) ---------
__global__ __launch_bounds__(256) void k_convert_x(const void* __restrict__ src,
                                                   __bf16* __restrict__ dst,
                                                   float* __restrict__ nsum) {
  if (blockIdx.x == 0) {
#pragma unroll
    for (int j = 0; j < 16; ++j) nsum[threadIdx.x + j * 256] = 0.f;  // 4096 floats
  }
  const int i = (blockIdx.x * 256 + threadIdx.x) * 8;  // < 16777216
  if (detect_f32((const unsigned int*)src)) {
    const float* s = (const float*)src;
    bf16x8 v;
#pragma unroll
    for (int j = 0; j < 8; ++j) v[j] = (__bf16)s[i + j];
    *(bf16x8*)(dst + i) = v;
  } else {
    *(bf16x8*)(dst + i) = *(const bf16x8*)((const __bf16*)src + i);
  }
}

// ---------------- K0b: canonicalize the 11 weight/bias/temp inputs -----------
__global__ __launch_bounds__(256) void k_convert_w(
    const void* s0, const void* s1, const void* s2, const void* s3, const void* s4,
    const void* s5, const void* s6, const void* s7, const void* s8, const void* s9,
    const void* s10, __bf16* __restrict__ cw, const void* __restrict__ xsrc) {
  const int i = (blockIdx.x * 256 + threadIdx.x) * 8;
  if (i >= 1376656) return;
  const void* s;
  int base;
  if (i < 262144)        { s = s0;  base = 0; }
  else if (i < 786432)   { s = s1;  base = 262144; }
  else if (i < 786496)   { s = s2;  base = 786432; }
  else if (i < 1310784)  { s = s3;  base = 786496; }
  else if (i < 1310848)  { s = s4;  base = 1310784; }
  else if (i < 1343616)  { s = s5;  base = 1310848; }
  else if (i < 1343744)  { s = s6;  base = 1343616; }
  else if (i < 1376512)  { s = s7;  base = 1343744; }
  else if (i < 1376640)  { s = s8;  base = 1376512; }
  else if (i < 1376648)  { s = s9;  base = 1376640; }
  else                   { s = s10; base = 1376648; }
  const int li = i - base;
  if (detect_f32((const unsigned int*)xsrc)) {
    const float* sf = (const float*)s;
#pragma unroll
    for (int j = 0; j < 8; ++j) cw[i + j] = (__bf16)sf[li + j];
  } else {
    const __bf16* sb = (const __bf16*)s;
#pragma unroll
    for (int j = 0; j < 8; ++j) cw[i + j] = sb[li + j];
  }
}

// ---------------- K1: qkvv = x @ Wqkvv^T (transposed store) + q/k norm sums --
__global__ __launch_bounds__(256) void k_qkvv(const __bf16* __restrict__ x,
                                              const __bf16* __restrict__ Wq,
                                              __bf16* __restrict__ qkvv,
                                              float* __restrict__ qsum,
                                              float* __restrict__ ksum) {
  __shared__ alignas(16) __bf16 As[128 * 32];
  __shared__ alignas(16) __bf16 Bs[128 * 32];
  const int t = threadIdx.x, lane = t & 63;
  const int wr = t >> 7, wc = (t >> 6) & 1;
  const int l15 = lane & 15, g = lane >> 4;
  const int f0 = blockIdx.y * 128;
  const int t0 = blockIdx.x * 128;
  f32x4 acc[4][4] = {};
  const int r = t >> 2;
  const int c8 = ((t & 3) ^ ((t >> 3) & 3)) * 8;        // staged (swizzled) chunk
  const int cx = ((g ^ ((l15 >> 1) & 3)) * 8);          // read-side chunk
  for (int k0 = 0; k0 < 256; k0 += 32) {
#pragma unroll
    for (int i = 0; i < 2; ++i) {
      gl2lds16(Wq + (size_t)(f0 + i * 64 + r) * 256 + k0 + c8, As + i * 2048 + t * 8);
      gl2lds16(x + (size_t)(t0 + i * 64 + r) * 256 + k0 + c8, Bs + i * 2048 + t * 8);
    }
    __syncthreads();
    bf16x8 af[4], bfr[4];
#pragma unroll
    for (int i = 0; i < 4; ++i) {
      af[i] = *(const bf16x8*)(As + (wr * 64 + i * 16 + l15) * 32 + cx);
      bfr[i] = *(const bf16x8*)(Bs + (wc * 64 + i * 16 + l15) * 32 + cx);
    }
#pragma unroll
    for (int i = 0; i < 4; ++i)
#pragma unroll
      for (int j = 0; j < 4; ++j) acc[i][j] = MFMA(af[i], bfr[j], acc[i][j]);
    __syncthreads();
  }
  const int b = t0 >> 13;
#pragma unroll
  for (int i = 0; i < 4; ++i) {
#pragma unroll
    for (int j = 0; j < 4; ++j) {
      const int tok = t0 + wc * 64 + j * 16 + l15;
      const int n = tok & 8191;
#pragma unroll
      for (int rr = 0; rr < 4; ++rr) {
        const int f = f0 + wr * 64 + i * 16 + g * 4 + rr;
        qkvv[(size_t)(((f >> 8) * 8 + b) * 256 + (f & 255)) * 8192 + n] = (__bf16)acc[i][j][rr];
      }
    }
  }
  // fused L2-norm partial sums for q (f<256) and k (256<=f<512)
  if (f0 < 512) {
    float* dst = (f0 >> 8) ? ksum : qsum;
#pragma unroll
    for (int i = 0; i < 4; ++i) {
#pragma unroll
      for (int rr = 0; rr < 4; ++rr) {
        float s = 0.f;
#pragma unroll
        for (int j = 0; j < 4; ++j) {
          const float v = acc[i][j][rr];
          s += v * v;
        }
#pragma unroll
        for (int off = 1; off < 16; off <<= 1) s += __shfl_xor(s, off, 16);
        if (l15 == 0) {
          const int f = f0 + wr * 64 + i * 16 + g * 4 + rr;
          atomicAdd(dst + b * 256 + (f & 255), s);
        }
      }
    }
  }
}

// ---------------- K3: k_proj / v_proj partial GEMMs (K-split) ----------------
__global__ __launch_bounds__(256) void k_proj_part(const __bf16* __restrict__ qkvv,
                                                   const __bf16* __restrict__ WE,
                                                   const __bf16* __restrict__ WF,
                                                   float* __restrict__ pbuf) {
  __shared__ alignas(16) __bf16 As[128 * 32];
  __shared__ alignas(16) __bf16 Bs[64 * 32];
  const int t = threadIdx.x, lane = t & 63;
  const int wr = t >> 7, wc = (t >> 6) & 1;
  const int l15 = lane & 15, g = lane >> 4;
  const int kc = blockIdx.x, mt = blockIdx.y, pj = blockIdx.z;
  const __bf16* A = qkvv + (size_t)(pj ? 3 : 1) * 2048 * 8192;
  const __bf16* Bm = pj ? WF : WE;
  const int r0 = mt * 128;
  f32x4 acc[4][2] = {};
  const int r = t >> 2;
  const int c8 = ((t & 3) ^ ((t >> 3) & 3)) * 8;
  const int cx = ((g ^ ((l15 >> 1) & 3)) * 8);
  for (int k0 = kc * 512; k0 < kc * 512 + 512; k0 += 32) {
#pragma unroll
    for (int i = 0; i < 2; ++i)
      gl2lds16(A + (size_t)(r0 + i * 64 + r) * 8192 + k0 + c8, As + i * 2048 + t * 8);
    gl2lds16(Bm + (size_t)r * 8192 + k0 + c8, Bs + t * 8);
    __syncthreads();
    bf16x8 af[4], bfr[2];
#pragma unroll
    for (int i = 0; i < 4; ++i)
      af[i] = *(const bf16x8*)(As + (wr * 64 + i * 16 + l15) * 32 + cx);
#pragma unroll
    for (int j = 0; j < 2; ++j)
      bfr[j] = *(const bf16x8*)(Bs + (wc * 32 + j * 16 + l15) * 32 + cx);
#pragma unroll
    for (int i = 0; i < 4; ++i)
#pragma unroll
      for (int j = 0; j < 2; ++j) acc[i][j] = MFMA(af[i], bfr[j], acc[i][j]);
    __syncthreads();
  }
  float* dst = pbuf + (size_t)((pj * 16 + kc) * 2048 + r0) * 64;
#pragma unroll
  for (int i = 0; i < 4; ++i)
#pragma unroll
    for (int j = 0; j < 2; ++j)
#pragma unroll
      for (int rr = 0; rr < 4; ++rr)
        dst[(wr * 64 + i * 16 + g * 4 + rr) * 64 + wc * 32 + j * 16 + l15] = acc[i][j][rr];
}

// ---------------- K3b: reduce + bias; emit bf16 MFMA-operand copies ----------
// kprojT[bh][p][d] = (kproj + bE) * qinv[bh,d] * temp2[h]   (A-operand, logits)
// vprojb[bh][d][p] = (vproj + bF)                            (A-operand, PV)
__global__ __launch_bounds__(256) void k_proj_reduce(const float* __restrict__ pbuf,
                                                     const __bf16* __restrict__ bE,
                                                     const __bf16* __restrict__ bF,
                                                     const float* __restrict__ qsum,
                                                     const __bf16* __restrict__ t2,
                                                     __bf16* __restrict__ kprojT,
                                                     __bf16* __restrict__ vprojb) {
  const int idx = blockIdx.x * 256 + threadIdx.x;  // [0, 262144)
  const int pj = idx >> 17, rp = idx & 131071, p = idx & 63;
  const int row = rp >> 6, bh = row >> 5, d = row & 31, h = bh & 7;
  float s = (float)((pj ? bF : bE)[p]);
  const float* src = pbuf + (size_t)pj * 16 * 131072 + rp;
#pragma unroll
  for (int k = 0; k < 16; ++k) s += src[(size_t)k * 131072];
  if (pj == 0) {
    const float qi = 1.0f / fmaxf(sqrtf(qsum[row]), 1e-12f);
    kprojT[bh * 2048 + p * 32 + d] = (__bf16)(s * qi * (float)t2[h]);
  } else {
    vprojb[bh * 2048 + d * 64 + p] = (__bf16)s;
  }
}

// ---------------- K4a: S[d,e] = q . k partials (K-split 8 x 4 waves) ---------
__global__ __launch_bounds__(256) void k_sca_part(const __bf16* __restrict__ qkvv,
                                                  float* __restrict__ spart) {
  const int bh = blockIdx.x, kc = blockIdx.y;
  const int t = threadIdx.x, lane = t & 63, w = t >> 6;
  const __bf16* qb = qkvv + (size_t)(bh * 32) * 8192;
  const __bf16* kb = qkvv + (size_t)(2048 + bh * 32) * 8192;
  f32x4 acc[2][2] = {};
  const int kbase = kc * 1024 + w * 256 + (lane >> 4) * 8;
#pragma unroll
  for (int ks = 0; ks < 256; ks += 32) {
    bf16x8 af[2], bfr[2];
#pragma unroll
    for (int i = 0; i < 2; ++i) {
      af[i] = *(const bf16x8*)(qb + (size_t)(i * 16 + (lane & 15)) * 8192 + kbase + ks);
      bfr[i] = *(const bf16x8*)(kb + (size_t)(i * 16 + (lane & 15)) * 8192 + kbase + ks);
    }
#pragma unroll
    for (int i = 0; i < 2; ++i)
#pragma unroll
      for (int j = 0; j < 2; ++j) acc[i][j] = MFMA(af[i], bfr[j], acc[i][j]);
  }
  float* dst = spart + (size_t)((bh * 8 + kc) * 4 + w) * 1024;
#pragma unroll
  for (int i = 0; i < 2; ++i)
#pragma unroll
    for (int j = 0; j < 2; ++j)
#pragma unroll
      for (int rr = 0; rr < 4; ++rr)
        dst[(i * 16 + (lane >> 4) * 4 + rr) * 32 + j * 16 + (lane & 15)] = acc[i][j][rr];
}

// ---------------- K4b: reduce, scale, softmax over e; emit bf16 attn [d][e] --
__global__ __launch_bounds__(256) void k_sca_softmax(const float* __restrict__ spart,
                                                     const float* __restrict__ qsum,
                                                     const float* __restrict__ ksum,
                                                     const __bf16* __restrict__ temp1,
                                                     __bf16* __restrict__ attnb) {
  const int bh = blockIdx.x;
  __shared__ float S[1024];
  const int t = threadIdx.x;
  const float tmp = (float)temp1[bh & 7];
  for (int idx = t; idx < 1024; idx += 256) {
    float s = 0.f;
    const float* src = spart + (size_t)bh * 32768 + idx;
#pragma unroll
    for (int k = 0; k < 32; ++k) s += src[k * 1024];
    const float qi = 1.0f / fmaxf(sqrtf(qsum[bh * 32 + (idx >> 5)]), 1e-12f);
    const float ki = 1.0f / fmaxf(sqrtf(ksum[bh * 32 + (idx & 31)]), 1e-12f);
    S[idx] = s * qi * ki * tmp;
  }
  __syncthreads();
  const int lane = t & 63, w = t >> 6;
#pragma unroll
  for (int rr = 0; rr < 4; ++rr) {
    const int row = rr * 8 + w * 2 + (lane >> 5);
    const int e = lane & 31;
    float v = S[row * 32 + e];
    float m = v;
#pragma unroll
    for (int off = 16; off; off >>= 1) m = fmaxf(m, __shfl_xor(m, off, 32));
    const float ex = __expf(v - m);
    float sm = ex;
#pragma unroll
    for (int off = 16; off; off >>= 1) sm += __shfl_xor(sm, off, 32);
    attnb[(size_t)bh * 1024 + row * 32 + e] = (__bf16)(ex / sm);
  }
}

// ---------------- K4c/K5 merged: channel-attn apply + spatial attention ------
__global__ __launch_bounds__(256) void k_casa(const __bf16* __restrict__ qkvv,
                                              const __bf16* __restrict__ attnb,
                                              const __bf16* __restrict__ kprojT,
                                              const __bf16* __restrict__ vprojb,
                                              __bf16* __restrict__ xca,
                                              __bf16* __restrict__ xsa) {
  __shared__ __bf16 P[4][16 * 72];  // used by the sa branch only
  const int t = threadIdx.x, lane = t & 63, w = t >> 6;
  const int l15 = lane & 15, g = lane >> 4;
  if (blockIdx.y < 64) {
    // ---- channel attention: x_ca[d][tok] = sum_e attn[d][e] * v_ca[e][tok]
    const int bh = blockIdx.y, b = bh >> 3, h = bh & 7;
    const __bf16* vb = qkvv + (size_t)(4096 + bh * 32) * 8192;
    bf16x8 aa[2];
#pragma unroll
    for (int mi = 0; mi < 2; ++mi)
      aa[mi] = *(const bf16x8*)(attnb + bh * 1024 + (mi * 16 + l15) * 32 + g * 8);
#pragma unroll
    for (int it = 0; it < 4; ++it) {
      const int n = blockIdx.x * 256 + it * 64 + w * 16 + l15;
      union { bf16x8 v; unsigned short u[8]; } bq;
#pragma unroll
      for (int j = 0; j < 8; ++j)
        bq.u[j] = *(const unsigned short*)(vb + (size_t)(g * 8 + j) * 8192 + n);
      f32x4 o[2] = {};
#pragma unroll
      for (int mi = 0; mi < 2; ++mi) o[mi] = MFMA(aa[mi], bq.v, o[mi]);
#pragma unroll
      for (int mi = 0; mi < 2; ++mi) {
        bf16x4 p4;
#pragma unroll
        for (int rr = 0; rr < 4; ++rr) p4[rr] = (__bf16)o[mi][rr];
        *(bf16x4*)(xca + (size_t)(b * 8192 + n) * 256 + h * 32 + mi * 16 + g * 4) = p4;
      }
    }
  } else {
    // ---- spatial (low-rank) attention
    const int bh = blockIdx.y - 64;
    const __bf16* qb = qkvv + (size_t)(bh * 32) * 8192;
    bf16x8 ka[4], va[2][2];
#pragma unroll
    for (int tile = 0; tile < 4; ++tile)
      ka[tile] = *(const bf16x8*)(kprojT + bh * 2048 + (tile * 16 + l15) * 32 + g * 8);
#pragma unroll
    for (int mi = 0; mi < 2; ++mi)
#pragma unroll
      for (int kh = 0; kh < 2; ++kh)
        va[mi][kh] = *(const bf16x8*)(vprojb + bh * 2048 + (mi * 16 + l15) * 64 + kh * 32 + g * 8);
    __bf16* Pw = &P[w][0];
#pragma unroll
    for (int it = 0; it < 4; ++it) {
      const int n0 = blockIdx.x * 256 + it * 64 + w * 16;
      union { bf16x8 v; unsigned short u[8]; } bq;
#pragma unroll
      for (int j = 0; j < 8; ++j)
        bq.u[j] = *(const unsigned short*)(qb + (size_t)(g * 8 + j) * 8192 + n0 + l15);
      f32x4 st[4];
#pragma unroll
      for (int tile = 0; tile < 4; ++tile) {
        f32x4 z = {};
        st[tile] = MFMA(ka[tile], bq.v, z);
      }
      float m = st[0][0];
#pragma unroll
      for (int tile = 0; tile < 4; ++tile)
#pragma unroll
        for (int rr = 0; rr < 4; ++rr) m = fmaxf(m, st[tile][rr]);
      m = fmaxf(m, __shfl_xor(m, 16, 64));
      m = fmaxf(m, __shfl_xor(m, 32, 64));
      float sum = 0.f;
#pragma unroll
      for (int tile = 0; tile < 4; ++tile) {
        bf16x4 p4;
#pragma unroll
        for (int rr = 0; rr < 4; ++rr) {
          const float ex = __expf(st[tile][rr] - m);
          sum += ex;
          p4[rr] = (__bf16)ex;
        }
        *(bf16x4*)(Pw + l15 * 72 + tile * 16 + g * 4) = p4;
      }
      sum += __shfl_xor(sum, 16, 64);
      sum += __shfl_xor(sum, 32, 64);
      const float inv = 1.0f / sum;
      f32x4 o[2] = {};
#pragma unroll
      for (int kh = 0; kh < 2; ++kh) {
        const bf16x8 pf = *(const bf16x8*)(Pw + l15 * 72 + kh * 32 + g * 8);
#pragma unroll
        for (int mi = 0; mi < 2; ++mi) o[mi] = MFMA(va[mi][kh], pf, o[mi]);
      }
#pragma unroll
      for (int mi = 0; mi < 2; ++mi)
#pragma unroll
        for (int rr = 0; rr < 4; ++rr) {
          const int d = mi * 16 + g * 4 + rr;
          xsa[(size_t)(bh * 32 + d) * 8192 + n0 + l15] = (__bf16)(o[mi][rr] * inv);
        }
    }
  }
}

// ---------------- K6: output projections (both halves) -----------------------
__global__ __launch_bounds__(256) void k_out(const __bf16* __restrict__ xsa,
                                             const __bf16* __restrict__ xca,
                                             const __bf16* __restrict__ Wo1,
                                             const __bf16* __restrict__ bo1,
                                             const __bf16* __restrict__ Wo2,
                                             const __bf16* __restrict__ bo2,
                                             void* __restrict__ outv,
                                             const void* __restrict__ xsrc) {
  __shared__ alignas(16) __bf16 As[128 * 32];
  __shared__ alignas(16) __bf16 Bs[128 * 32];
  const int t = threadIdx.x, lane = t & 63;
  const int wr = t >> 7, wc = (t >> 6) & 1;
  const int l15 = lane & 15, g = lane >> 4;
  const int nt = blockIdx.x, b = blockIdx.y, br = blockIdx.z;
  const int isf32 = detect_f32((const unsigned int*)xsrc);
  const __bf16* Wo = br ? Wo2 : Wo1;
  const __bf16* bo = br ? bo2 : bo1;
  f32x4 acc[4][4] = {};
  const int r = t >> 2;
  const int c8 = ((t & 3) ^ ((t >> 3) & 3)) * 8;
  const int cx = ((g ^ ((l15 >> 1) & 3)) * 8);
  for (int k0 = 0; k0 < 256; k0 += 32) {
#pragma unroll
    for (int i = 0; i < 2; ++i) {
      const int row = nt * 128 + i * 64 + r;
      const __bf16* ga;
      if (br == 0) {
        // x_sa_mat[b,row,c] = xsa[b][(row>>5)&7][row>>8][(row&31)*256 + c]
        ga = xsa + (size_t)((b * 8 + ((row >> 5) & 7)) * 32 + (row >> 8)) * 8192 +
             (row & 31) * 256 + k0 + c8;
      } else {
        ga = xca + (size_t)(b * 8192 + row) * 256 + k0 + c8;
      }
      gl2lds16(ga, As + i * 2048 + t * 8);
      gl2lds16(Wo + (size_t)(i * 64 + r) * 256 + k0 + c8, Bs + i * 2048 + t * 8);
    }
    __syncthreads();
    bf16x8 af[4], bfr[4];
#pragma unroll
    for (int i = 0; i < 4; ++i) {
      af[i] = *(const bf16x8*)(As + (wr * 64 + i * 16 + l15) * 32 + cx);
      bfr[i] = *(const bf16x8*)(Bs + (wc * 64 + i * 16 + l15) * 32 + cx);
    }
#pragma unroll
    for (int i = 0; i < 4; ++i)
#pragma unroll
      for (int j = 0; j < 4; ++j) acc[i][j] = MFMA(af[i], bfr[j], acc[i][j]);
    __syncthreads();
  }
  float bias[4];
#pragma unroll
  for (int j = 0; j < 4; ++j) bias[j] = (float)bo[wc * 64 + j * 16 + l15];
#pragma unroll
  for (int i = 0; i < 4; ++i) {
#pragma unroll
    for (int j = 0; j < 4; ++j) {
      const int col = wc * 64 + j * 16 + l15;
#pragma unroll
      for (int rr = 0; rr < 4; ++rr) {
        const int row = nt * 128 + wr * 64 + i * 16 + g * 4 + rr;
        const float val = acc[i][j][rr] + bias[j];
        const size_t oi = (size_t)(b * 8192 + row) * 256 + br * 128 + col;
        if (isf32) ((float*)outv)[oi] = val;
        else ((__bf16*)outv)[oi] = (__bf16)val;
      }
    }
  }
}

extern "C" void kernel_launch(void* const* d_in, const int* in_sizes, int n_in,
                              void* d_out, int out_size, void* d_ws, size_t ws_size,
                              hipStream_t stream) {
  char* ws = (char*)d_ws;
  __bf16* qkvv   = (__bf16*)(ws);                    // 134,217,728 B
  __bf16* cinx   = (__bf16*)(ws + 134217728ull);     //  32 MB (region A)
  __bf16* xca    = (__bf16*)(ws + 134217728ull);     //  alias A (cinx dead after k_qkvv)
  float*  pbuf   = (float*)(ws + 167772160ull);      //  16 MB (region B)
  float*  spart  = (float*)(ws + 184549376ull);      //   8 MB (region B + 16M)
  __bf16* xsa    = (__bf16*)(ws + 167772160ull);     //  alias B (pbuf/spart dead by then)
  __bf16* kprojT = (__bf16*)(ws + 201326592ull);     //  262,144 B
  __bf16* vprojb = (__bf16*)(ws + 201588736ull);     //  262,144 B
  float*  qsum   = (float*)(ws + 201850880ull);      //    8,192 B
  float*  ksum   = (float*)(ws + 201859072ull);      //    8,192 B  (contiguous w/ qsum)
  __bf16* attnb  = (__bf16*)(ws + 201867264ull);     //  131,072 B
  __bf16* cw     = (__bf16*)(ws + 201998336ull);     //  2,753,536 B

  __bf16* cWq  = cw;
  __bf16* cWE  = cw + 262144;
  __bf16* cbE  = cw + 786432;
  __bf16* cWF  = cw + 786496;
  __bf16* cbF  = cw + 1310784;
  __bf16* cWo1 = cw + 1310848;
  __bf16* cbo1 = cw + 1343616;
  __bf16* cWo2 = cw + 1343744;
  __bf16* cbo2 = cw + 1376512;
  __bf16* ct1  = cw + 1376640;
  __bf16* ct2  = cw + 1376648;

  k_convert_x<<<8192, 256, 0, stream>>>(d_in[0], cinx, qsum);
  k_convert_w<<<673, 256, 0, stream>>>(d_in[1], d_in[2], d_in[3], d_in[4], d_in[5],
                                       d_in[6], d_in[7], d_in[8], d_in[9], d_in[10],
                                       d_in[11], cw, d_in[0]);
  k_qkvv<<<dim3(512, 8), 256, 0, stream>>>(cinx, cWq, qkvv, qsum, ksum);
  k_proj_part<<<dim3(16, 16, 2), 256, 0, stream>>>(qkvv, cWE, cWF, pbuf);
  k_proj_reduce<<<dim3(1024), 256, 0, stream>>>(pbuf, cbE, cbF, qsum, ct2, kprojT, vprojb);
  k_sca_part<<<dim3(64, 8), 256, 0, stream>>>(qkvv, spart);
  k_sca_softmax<<<dim3(64), 256, 0, stream>>>(spart, qsum, ksum, ct1, attnb);
  k_casa<<<dim3(32, 128), 256, 0, stream>>>(qkvv, attnb, kprojT, vprojb, xca, xsa);
  k_out<<<dim3(64, 8, 2), 256, 0, stream>>>(xsa, xca, cWo1, cbo1, cWo2, cbo2, d_out, d_in[0]);
}

// Round 5
// 311.549 us; speedup vs baseline: 1.5372x; 1.0591x over previous
//
#include <hip/hip_runtime.h>
#include <hip/hip_bf16.h>
#include <stdint.h>

// Problem: B=8, N=8192, C=256, H=8, D=32, P=64, F=4C=1024
// qkvv layout: [part(4)][b(8)][h*32+d(256)][n(8192)] bf16, n contiguous.
// Inputs self-detected as fp32-or-bf16; canonicalized to bf16 workspace buffers.
// K-loop LDS tiles use XOR chunk swizzle; qkvv epilogue does an LDS transpose
// so global writes are full 256B-per-row lines (no write-allocate RMW).
// L2-norm sums: per-block partials (npart) + k_nred reduction (no atomics).

typedef __attribute__((ext_vector_type(8))) __bf16 bf16x8;
typedef __attribute__((ext_vector_type(4))) __bf16 bf16x4;
typedef __attribute__((ext_vector_type(4))) float f32x4;

#define MFMA(a, b, c) __builtin_amdgcn_mfma_f32_16x16x32_bf16((a), (b), (c), 0, 0, 0)

__device__ __forceinline__ void gl2lds16(const __bf16* g, __bf16* l) {
  __builtin_amdgcn_global_load_lds(
      (const __attribute__((address_space(1))) void*)(const void*)g,
      (__attribute__((address_space(3))) void*)(void*)l, 16, 0, 0);
}

// Self-detect: sample x's first 64 dwords (uniform scalar loads). fp32 data's
// low halfwords are mantissa bytes -> exponent field >= 0xC0 w.p. ~1/4; real
// bf16 N(0,1)-scale data never has exp >= 0xC0.
__device__ __forceinline__ int detect_f32(const unsigned int* __restrict__ xw) {
  int c = 0;
#pragma unroll
  for (int i = 0; i < 64; ++i) {
    const unsigned int u = xw[i];
    c += (((u >> 7) & 0xFF) >= 0xC0) ? 1 : 0;
    c += (((u >> 23) & 0xFF) >= 0xC0) ? 1 : 0;
  }
  return c > 8;
}

// ---------------- K0a: canonicalize x ----------------------------------------
__global__ __launch_bounds__(256) void k_convert_x(const void* __restrict__ src,
                                                   __bf16* __restrict__ dst) {
  const int i = (blockIdx.x * 256 + threadIdx.x) * 8;  // < 16777216
  if (detect_f32((const unsigned int*)src)) {
    const float* s = (const float*)src;
    bf16x8 v;
#pragma unroll
    for (int j = 0; j < 8; ++j) v[j] = (__bf16)s[i + j];
    *(bf16x8*)(dst + i) = v;
  } else {
    *(bf16x8*)(dst + i) = *(const bf16x8*)((const __bf16*)src + i);
  }
}

// ---------------- K0b: canonicalize the 11 weight/bias/temp inputs -----------
__global__ __launch_bounds__(256) void k_convert_w(
    const void* s0, const void* s1, const void* s2, const void* s3, const void* s4,
    const void* s5, const void* s6, const void* s7, const void* s8, const void* s9,
    const void* s10, __bf16* __restrict__ cw, const void* __restrict__ xsrc) {
  const int i = (blockIdx.x * 256 + threadIdx.x) * 8;
  if (i >= 1376656) return;
  const void* s;
  int base;
  if (i < 262144)        { s = s0;  base = 0; }
  else if (i < 786432)   { s = s1;  base = 262144; }
  else if (i < 786496)   { s = s2;  base = 786432; }
  else if (i < 1310784)  { s = s3;  base = 786496; }
  else if (i < 1310848)  { s = s4;  base = 1310784; }
  else if (i < 1343616)  { s = s5;  base = 1310848; }
  else if (i < 1343744)  { s = s6;  base = 1343616; }
  else if (i < 1376512)  { s = s7;  base = 1343744; }
  else if (i < 1376640)  { s = s8;  base = 1376512; }
  else if (i < 1376648)  { s = s9;  base = 1376640; }
  else                   { s = s10; base = 1376648; }
  const int li = i - base;
  if (detect_f32((const unsigned int*)xsrc)) {
    const float* sf = (const float*)s;
#pragma unroll
    for (int j = 0; j < 8; ++j) cw[i + j] = (__bf16)sf[li + j];
  } else {
    const __bf16* sb = (const __bf16*)s;
#pragma unroll
    for (int j = 0; j < 8; ++j) cw[i + j] = sb[li + j];
  }
}

// ---------------- K1: qkvv = x @ Wqkvv^T (transposed store, full-line writes) -
__global__ __launch_bounds__(256) void k_qkvv(const __bf16* __restrict__ x,
                                              const __bf16* __restrict__ Wq,
                                              __bf16* __restrict__ qkvv,
                                              float* __restrict__ npart) {
  __shared__ alignas(16) __bf16 As[128 * 32];
  __shared__ alignas(16) __bf16 Bs[128 * 32];
  __shared__ alignas(16) __bf16 Cs[32 * 136];  // transpose tile, padded stride
  const int t = threadIdx.x, lane = t & 63;
  const int wr = t >> 7, wc = (t >> 6) & 1;
  const int l15 = lane & 15, g = lane >> 4;
  const int f0 = blockIdx.y * 128;
  const int t0 = blockIdx.x * 128;
  f32x4 acc[4][4] = {};
  const int r = t >> 2;
  const int c8 = ((t & 3) ^ ((t >> 3) & 3)) * 8;  // staged (swizzled) chunk
  const int cx = ((g ^ ((l15 >> 1) & 3)) * 8);    // read-side chunk
  for (int k0 = 0; k0 < 256; k0 += 32) {
#pragma unroll
    for (int i = 0; i < 2; ++i) {
      gl2lds16(Wq + (size_t)(f0 + i * 64 + r) * 256 + k0 + c8, As + i * 2048 + t * 8);
      gl2lds16(x + (size_t)(t0 + i * 64 + r) * 256 + k0 + c8, Bs + i * 2048 + t * 8);
    }
    __syncthreads();
    bf16x8 af[4], bfr[4];
#pragma unroll
    for (int i = 0; i < 4; ++i) {
      af[i] = *(const bf16x8*)(As + (wr * 64 + i * 16 + l15) * 32 + cx);
      bfr[i] = *(const bf16x8*)(Bs + (wc * 64 + i * 16 + l15) * 32 + cx);
    }
#pragma unroll
    for (int i = 0; i < 4; ++i)
#pragma unroll
      for (int j = 0; j < 4; ++j) acc[i][j] = MFMA(af[i], bfr[j], acc[i][j]);
    __syncthreads();
  }
  const int b = t0 >> 13;
  const int n0 = t0 & 8191;
  // Epilogue: per 32-f slab, stage to LDS, emit 256B-dense row stores + norm partials.
  for (int i = 0; i < 4; ++i) {
    if (i) __syncthreads();  // protect Cs from previous iteration's readers
#pragma unroll
    for (int j = 0; j < 4; ++j)
#pragma unroll
      for (int rr = 0; rr < 4; ++rr)
        Cs[(wr * 16 + g * 4 + rr) * 136 + wc * 64 + j * 16 + l15] = (__bf16)acc[i][j][rr];
    __syncthreads();
#pragma unroll
    for (int half = 0; half < 2; ++half) {
      const int row_l = (t >> 4) + half * 16;     // [0,32): 16 threads per row
      const int col8 = (t & 15) * 8;              // [0,128) in steps of 8
      const bf16x8 v = *(const bf16x8*)(Cs + row_l * 136 + col8);
      const int f = f0 + (row_l >> 4) * 64 + i * 16 + (row_l & 15);
      *(bf16x8*)(qkvv + (size_t)(((f >> 8) * 8 + b) * 256 + (f & 255)) * 8192 + n0 + col8) = v;
      if (f0 < 512) {  // q (f<256) and k (256<=f<512) L2-norm partial sums
        float s = 0.f;
#pragma unroll
        for (int jj = 0; jj < 8; ++jj) { const float q = (float)v[jj]; s += q * q; }
#pragma unroll
        for (int off = 1; off < 16; off <<= 1) s += __shfl_xor(s, off, 16);
        if ((t & 15) == 0) npart[(size_t)blockIdx.x * 512 + f] = s;
      }
    }
  }
}

// ---------------- K1b: reduce norm partials over the 64 token-blocks of each b
__global__ __launch_bounds__(256) void k_nred(const float* __restrict__ npart,
                                              float* __restrict__ qsum,
                                              float* __restrict__ ksum) {
  const int which = blockIdx.x >> 3, b = blockIdx.x & 7;
  const int c = threadIdx.x;
  float s = 0.f;
#pragma unroll 4
  for (int j = 0; j < 64; ++j)
    s += npart[(size_t)(b * 64 + j) * 512 + which * 256 + c];
  (which ? ksum : qsum)[b * 256 + c] = s;
}

// ---------------- K3: k_proj / v_proj partial GEMMs (K-split) ----------------
__global__ __launch_bounds__(256) void k_proj_part(const __bf16* __restrict__ qkvv,
                                                   const __bf16* __restrict__ WE,
                                                   const __bf16* __restrict__ WF,
                                                   float* __restrict__ pbuf) {
  __shared__ alignas(16) __bf16 As[128 * 32];
  __shared__ alignas(16) __bf16 Bs[64 * 32];
  const int t = threadIdx.x, lane = t & 63;
  const int wr = t >> 7, wc = (t >> 6) & 1;
  const int l15 = lane & 15, g = lane >> 4;
  const int kc = blockIdx.x, mt = blockIdx.y, pj = blockIdx.z;
  const __bf16* A = qkvv + (size_t)(pj ? 3 : 1) * 2048 * 8192;
  const __bf16* Bm = pj ? WF : WE;
  const int r0 = mt * 128;
  f32x4 acc[4][2] = {};
  const int r = t >> 2;
  const int c8 = ((t & 3) ^ ((t >> 3) & 3)) * 8;
  const int cx = ((g ^ ((l15 >> 1) & 3)) * 8);
  for (int k0 = kc * 512; k0 < kc * 512 + 512; k0 += 32) {
#pragma unroll
    for (int i = 0; i < 2; ++i)
      gl2lds16(A + (size_t)(r0 + i * 64 + r) * 8192 + k0 + c8, As + i * 2048 + t * 8);
    gl2lds16(Bm + (size_t)r * 8192 + k0 + c8, Bs + t * 8);
    __syncthreads();
    bf16x8 af[4], bfr[2];
#pragma unroll
    for (int i = 0; i < 4; ++i)
      af[i] = *(const bf16x8*)(As + (wr * 64 + i * 16 + l15) * 32 + cx);
#pragma unroll
    for (int j = 0; j < 2; ++j)
      bfr[j] = *(const bf16x8*)(Bs + (wc * 32 + j * 16 + l15) * 32 + cx);
#pragma unroll
    for (int i = 0; i < 4; ++i)
#pragma unroll
      for (int j = 0; j < 2; ++j) acc[i][j] = MFMA(af[i], bfr[j], acc[i][j]);
    __syncthreads();
  }
  float* dst = pbuf + (size_t)((pj * 16 + kc) * 2048 + r0) * 64;
#pragma unroll
  for (int i = 0; i < 4; ++i)
#pragma unroll
    for (int j = 0; j < 2; ++j)
#pragma unroll
      for (int rr = 0; rr < 4; ++rr)
        dst[(wr * 64 + i * 16 + g * 4 + rr) * 64 + wc * 32 + j * 16 + l15] = acc[i][j][rr];
}

// ---------------- K3b: reduce + bias; emit bf16 MFMA-operand copies ----------
__global__ __launch_bounds__(256) void k_proj_reduce(const float* __restrict__ pbuf,
                                                     const __bf16* __restrict__ bE,
                                                     const __bf16* __restrict__ bF,
                                                     const float* __restrict__ qsum,
                                                     const __bf16* __restrict__ t2,
                                                     __bf16* __restrict__ kprojT,
                                                     __bf16* __restrict__ vprojb) {
  const int idx = blockIdx.x * 256 + threadIdx.x;  // [0, 262144)
  const int pj = idx >> 17, rp = idx & 131071, p = idx & 63;
  const int row = rp >> 6, bh = row >> 5, d = row & 31, h = bh & 7;
  float s = (float)((pj ? bF : bE)[p]);
  const float* src = pbuf + (size_t)pj * 16 * 131072 + rp;
#pragma unroll
  for (int k = 0; k < 16; ++k) s += src[(size_t)k * 131072];
  if (pj == 0) {
    const float qi = 1.0f / fmaxf(sqrtf(qsum[row]), 1e-12f);
    kprojT[bh * 2048 + p * 32 + d] = (__bf16)(s * qi * (float)t2[h]);
  } else {
    vprojb[bh * 2048 + d * 64 + p] = (__bf16)s;
  }
}

// ---------------- K4a: S[d,e] = q . k partials (K-split 8 x 4 waves) ---------
__global__ __launch_bounds__(256) void k_sca_part(const __bf16* __restrict__ qkvv,
                                                  float* __restrict__ spart) {
  const int bh = blockIdx.x, kc = blockIdx.y;
  const int t = threadIdx.x, lane = t & 63, w = t >> 6;
  const __bf16* qb = qkvv + (size_t)(bh * 32) * 8192;
  const __bf16* kb = qkvv + (size_t)(2048 + bh * 32) * 8192;
  f32x4 acc[2][2] = {};
  const int kbase = kc * 1024 + w * 256 + (lane >> 4) * 8;
#pragma unroll
  for (int ks = 0; ks < 256; ks += 32) {
    bf16x8 af[2], bfr[2];
#pragma unroll
    for (int i = 0; i < 2; ++i) {
      af[i] = *(const bf16x8*)(qb + (size_t)(i * 16 + (lane & 15)) * 8192 + kbase + ks);
      bfr[i] = *(const bf16x8*)(kb + (size_t)(i * 16 + (lane & 15)) * 8192 + kbase + ks);
    }
#pragma unroll
    for (int i = 0; i < 2; ++i)
#pragma unroll
      for (int j = 0; j < 2; ++j) acc[i][j] = MFMA(af[i], bfr[j], acc[i][j]);
  }
  float* dst = spart + (size_t)((bh * 8 + kc) * 4 + w) * 1024;
#pragma unroll
  for (int i = 0; i < 2; ++i)
#pragma unroll
    for (int j = 0; j < 2; ++j)
#pragma unroll
      for (int rr = 0; rr < 4; ++rr)
        dst[(i * 16 + (lane >> 4) * 4 + rr) * 32 + j * 16 + (lane & 15)] = acc[i][j][rr];
}

// ---------------- K4b: reduce, scale, softmax over e; emit bf16 attn [d][e] --
__global__ __launch_bounds__(256) void k_sca_softmax(const float* __restrict__ spart,
                                                     const float* __restrict__ qsum,
                                                     const float* __restrict__ ksum,
                                                     const __bf16* __restrict__ temp1,
                                                     __bf16* __restrict__ attnb) {
  const int bh = blockIdx.x;
  __shared__ float S[1024];
  const int t = threadIdx.x;
  const float tmp = (float)temp1[bh & 7];
  for (int idx = t; idx < 1024; idx += 256) {
    float s = 0.f;
    const float* src = spart + (size_t)bh * 32768 + idx;
#pragma unroll
    for (int k = 0; k < 32; ++k) s += src[k * 1024];
    const float qi = 1.0f / fmaxf(sqrtf(qsum[bh * 32 + (idx >> 5)]), 1e-12f);
    const float ki = 1.0f / fmaxf(sqrtf(ksum[bh * 32 + (idx & 31)]), 1e-12f);
    S[idx] = s * qi * ki * tmp;
  }
  __syncthreads();
  const int lane = t & 63, w = t >> 6;
#pragma unroll
  for (int rr = 0; rr < 4; ++rr) {
    const int row = rr * 8 + w * 2 + (lane >> 5);
    const int e = lane & 31;
    float v = S[row * 32 + e];
    float m = v;
#pragma unroll
    for (int off = 16; off; off >>= 1) m = fmaxf(m, __shfl_xor(m, off, 32));
    const float ex = __expf(v - m);
    float sm = ex;
#pragma unroll
    for (int off = 16; off; off >>= 1) sm += __shfl_xor(sm, off, 32);
    attnb[(size_t)bh * 1024 + row * 32 + e] = (__bf16)(ex / sm);
  }
}

// ---------------- K4c/K5 merged: channel-attn apply + spatial attention ------
__global__ __launch_bounds__(256) void k_casa(const __bf16* __restrict__ qkvv,
                                              const __bf16* __restrict__ attnb,
                                              const __bf16* __restrict__ kprojT,
                                              const __bf16* __restrict__ vprojb,
                                              __bf16* __restrict__ xca,
                                              __bf16* __restrict__ xsa) {
  __shared__ __bf16 P[4][16 * 72];  // used by the sa branch only
  const int t = threadIdx.x, lane = t & 63, w = t >> 6;
  const int l15 = lane & 15, g = lane >> 4;
  if (blockIdx.y < 64) {
    // ---- channel attention: x_ca[d][tok] = sum_e attn[d][e] * v_ca[e][tok]
    const int bh = blockIdx.y, b = bh >> 3, h = bh & 7;
    const __bf16* vb = qkvv + (size_t)(4096 + bh * 32) * 8192;
    bf16x8 aa[2];
#pragma unroll
    for (int mi = 0; mi < 2; ++mi)
      aa[mi] = *(const bf16x8*)(attnb + bh * 1024 + (mi * 16 + l15) * 32 + g * 8);
#pragma unroll
    for (int it = 0; it < 4; ++it) {
      const int n = blockIdx.x * 256 + it * 64 + w * 16 + l15;
      union { bf16x8 v; unsigned short u[8]; } bq;
#pragma unroll
      for (int j = 0; j < 8; ++j)
        bq.u[j] = *(const unsigned short*)(vb + (size_t)(g * 8 + j) * 8192 + n);
      f32x4 o[2] = {};
#pragma unroll
      for (int mi = 0; mi < 2; ++mi) o[mi] = MFMA(aa[mi], bq.v, o[mi]);
#pragma unroll
      for (int mi = 0; mi < 2; ++mi) {
        bf16x4 p4;
#pragma unroll
        for (int rr = 0; rr < 4; ++rr) p4[rr] = (__bf16)o[mi][rr];
        *(bf16x4*)(xca + (size_t)(b * 8192 + n) * 256 + h * 32 + mi * 16 + g * 4) = p4;
      }
    }
  } else {
    // ---- spatial (low-rank) attention
    const int bh = blockIdx.y - 64;
    const __bf16* qb = qkvv + (size_t)(bh * 32) * 8192;
    bf16x8 ka[4], va[2][2];
#pragma unroll
    for (int tile = 0; tile < 4; ++tile)
      ka[tile] = *(const bf16x8*)(kprojT + bh * 2048 + (tile * 16 + l15) * 32 + g * 8);
#pragma unroll
    for (int mi = 0; mi < 2; ++mi)
#pragma unroll
      for (int kh = 0; kh < 2; ++kh)
        va[mi][kh] = *(const bf16x8*)(vprojb + bh * 2048 + (mi * 16 + l15) * 64 + kh * 32 + g * 8);
    __bf16* Pw = &P[w][0];
#pragma unroll
    for (int it = 0; it < 4; ++it) {
      const int n0 = blockIdx.x * 256 + it * 64 + w * 16;
      union { bf16x8 v; unsigned short u[8]; } bq;
#pragma unroll
      for (int j = 0; j < 8; ++j)
        bq.u[j] = *(const unsigned short*)(qb + (size_t)(g * 8 + j) * 8192 + n0 + l15);
      f32x4 st[4];
#pragma unroll
      for (int tile = 0; tile < 4; ++tile) {
        f32x4 z = {};
        st[tile] = MFMA(ka[tile], bq.v, z);
      }
      float m = st[0][0];
#pragma unroll
      for (int tile = 0; tile < 4; ++tile)
#pragma unroll
        for (int rr = 0; rr < 4; ++rr) m = fmaxf(m, st[tile][rr]);
      m = fmaxf(m, __shfl_xor(m, 16, 64));
      m = fmaxf(m, __shfl_xor(m, 32, 64));
      float sum = 0.f;
#pragma unroll
      for (int tile = 0; tile < 4; ++tile) {
        bf16x4 p4;
#pragma unroll
        for (int rr = 0; rr < 4; ++rr) {
          const float ex = __expf(st[tile][rr] - m);
          sum += ex;
          p4[rr] = (__bf16)ex;
        }
        *(bf16x4*)(Pw + l15 * 72 + tile * 16 + g * 4) = p4;
      }
      sum += __shfl_xor(sum, 16, 64);
      sum += __shfl_xor(sum, 32, 64);
      const float inv = 1.0f / sum;
      f32x4 o[2] = {};
#pragma unroll
      for (int kh = 0; kh < 2; ++kh) {
        const bf16x8 pf = *(const bf16x8*)(Pw + l15 * 72 + kh * 32 + g * 8);
#pragma unroll
        for (int mi = 0; mi < 2; ++mi) o[mi] = MFMA(va[mi][kh], pf, o[mi]);
      }
#pragma unroll
      for (int mi = 0; mi < 2; ++mi)
#pragma unroll
        for (int rr = 0; rr < 4; ++rr) {
          const int d = mi * 16 + g * 4 + rr;
          xsa[(size_t)(bh * 32 + d) * 8192 + n0 + l15] = (__bf16)(o[mi][rr] * inv);
        }
    }
  }
}

// ---------------- K6: output projections (both halves) -----------------------
__global__ __launch_bounds__(256) void k_out(const __bf16* __restrict__ xsa,
                                             const __bf16* __restrict__ xca,
                                             const __bf16* __restrict__ Wo1,
                                             const __bf16* __restrict__ bo1,
                                             const __bf16* __restrict__ Wo2,
                                             const __bf16* __restrict__ bo2,
                                             void* __restrict__ outv,
                                             const void* __restrict__ xsrc) {
  __shared__ alignas(16) __bf16 As[128 * 32];
  __shared__ alignas(16) __bf16 Bs[128 * 32];
  const int t = threadIdx.x, lane = t & 63;
  const int wr = t >> 7, wc = (t >> 6) & 1;
  const int l15 = lane & 15, g = lane >> 4;
  const int nt = blockIdx.x, b = blockIdx.y, br = blockIdx.z;
  const int isf32 = detect_f32((const unsigned int*)xsrc);
  const __bf16* Wo = br ? Wo2 : Wo1;
  const __bf16* bo = br ? bo2 : bo1;
  f32x4 acc[4][4] = {};
  const int r = t >> 2;
  const int c8 = ((t & 3) ^ ((t >> 3) & 3)) * 8;
  const int cx = ((g ^ ((l15 >> 1) & 3)) * 8);
  for (int k0 = 0; k0 < 256; k0 += 32) {
#pragma unroll
    for (int i = 0; i < 2; ++i) {
      const int row = nt * 128 + i * 64 + r;
      const __bf16* ga;
      if (br == 0) {
        // x_sa_mat[b,row,c] = xsa[b][(row>>5)&7][row>>8][(row&31)*256 + c]
        ga = xsa + (size_t)((b * 8 + ((row >> 5) & 7)) * 32 + (row >> 8)) * 8192 +
             (row & 31) * 256 + k0 + c8;
      } else {
        ga = xca + (size_t)(b * 8192 + row) * 256 + k0 + c8;
      }
      gl2lds16(ga, As + i * 2048 + t * 8);
      gl2lds16(Wo + (size_t)(i * 64 + r) * 256 + k0 + c8, Bs + i * 2048 + t * 8);
    }
    __syncthreads();
    bf16x8 af[4], bfr[4];
#pragma unroll
    for (int i = 0; i < 4; ++i) {
      af[i] = *(const bf16x8*)(As + (wr * 64 + i * 16 + l15) * 32 + cx);
      bfr[i] = *(const bf16x8*)(Bs + (wc * 64 + i * 16 + l15) * 32 + cx);
    }
#pragma unroll
    for (int i = 0; i < 4; ++i)
#pragma unroll
      for (int j = 0; j < 4; ++j) acc[i][j] = MFMA(af[i], bfr[j], acc[i][j]);
    __syncthreads();
  }
  float bias[4];
#pragma unroll
  for (int j = 0; j < 4; ++j) bias[j] = (float)bo[wc * 64 + j * 16 + l15];
#pragma unroll
  for (int i = 0; i < 4; ++i) {
#pragma unroll
    for (int j = 0; j < 4; ++j) {
      const int col = wc * 64 + j * 16 + l15;
#pragma unroll
      for (int rr = 0; rr < 4; ++rr) {
        const int row = nt * 128 + wr * 64 + i * 16 + g * 4 + rr;
        const float val = acc[i][j][rr] + bias[j];
        const size_t oi = (size_t)(b * 8192 + row) * 256 + br * 128 + col;
        if (isf32) ((float*)outv)[oi] = val;
        else ((__bf16*)outv)[oi] = (__bf16)val;
      }
    }
  }
}

extern "C" void kernel_launch(void* const* d_in, const int* in_sizes, int n_in,
                              void* d_out, int out_size, void* d_ws, size_t ws_size,
                              hipStream_t stream) {
  char* ws = (char*)d_ws;
  __bf16* qkvv   = (__bf16*)(ws);                    // 134,217,728 B
  __bf16* cinx   = (__bf16*)(ws + 134217728ull);     //  32 MB (region A)
  __bf16* xca    = (__bf16*)(ws + 134217728ull);     //  alias A (cinx dead after k_qkvv)
  float*  pbuf   = (float*)(ws + 167772160ull);      //  16 MB (region B)
  float*  npart  = (float*)(ws + 184549376ull);      //   1 MB (region C; dead after k_nred)
  float*  spart  = (float*)(ws + 184549376ull);      //   8 MB (alias C, written later)
  __bf16* xsa    = (__bf16*)(ws + 167772160ull);     //  alias B (pbuf/spart dead by then)
  __bf16* kprojT = (__bf16*)(ws + 201326592ull);     //  262,144 B
  __bf16* vprojb = (__bf16*)(ws + 201588736ull);     //  262,144 B
  float*  qsum   = (float*)(ws + 201850880ull);      //    8,192 B
  float*  ksum   = (float*)(ws + 201859072ull);      //    8,192 B
  __bf16* attnb  = (__bf16*)(ws + 201867264ull);     //  131,072 B
  __bf16* cw     = (__bf16*)(ws + 201998336ull);     //  2,753,536 B

  __bf16* cWq  = cw;
  __bf16* cWE  = cw + 262144;
  __bf16* cbE  = cw + 786432;
  __bf16* cWF  = cw + 786496;
  __bf16* cbF  = cw + 1310784;
  __bf16* cWo1 = cw + 1310848;
  __bf16* cbo1 = cw + 1343616;
  __bf16* cWo2 = cw + 1343744;
  __bf16* cbo2 = cw + 1376512;
  __bf16* ct1  = cw + 1376640;
  __bf16* ct2  = cw + 1376648;

  k_convert_x<<<8192, 256, 0, stream>>>(d_in[0], cinx);
  k_convert_w<<<673, 256, 0, stream>>>(d_in[1], d_in[2], d_in[3], d_in[4], d_in[5],
                                       d_in[6], d_in[7], d_in[8], d_in[9], d_in[10],
                                       d_in[11], cw, d_in[0]);
  k_qkvv<<<dim3(512, 8), 256, 0, stream>>>(cinx, cWq, qkvv, npart);
  k_nred<<<16, 256, 0, stream>>>(npart, qsum, ksum);
  k_proj_part<<<dim3(16, 16, 2), 256, 0, stream>>>(qkvv, cWE, cWF, pbuf);
  k_proj_reduce<<<dim3(1024), 256, 0, stream>>>(pbuf, cbE, cbF, qsum, ct2, kprojT, vprojb);
  k_sca_part<<<dim3(64, 8), 256, 0, stream>>>(qkvv, spart);
  k_sca_softmax<<<dim3(64), 256, 0, stream>>>(spart, qsum, ksum, ct1, attnb);
  k_casa<<<dim3(32, 128), 256, 0, stream>>>(qkvv, attnb, kprojT, vprojb, xca, xsa);
  k_out<<<dim3(64, 8, 2), 256, 0, stream>>>(xsa, xca, cWo1, cbo1, cWo2, cbo2, d_out, d_in[0]);
}